// Round 2
// baseline (45691.418 us; speedup 1.0000x reference)
//
#include <hip/hip_runtime.h>
#include <hip/hip_cooperative_groups.h>
#include <algorithm>

namespace cg = cooperative_groups;

typedef __bf16 bf16;
typedef __bf16 bf16x8 __attribute__((ext_vector_type(8)));
typedef float f32x4 __attribute__((ext_vector_type(4)));

// SEQ=256, B=128, XD=128, HD=1024, ZD=64
#define SEQ 256
#define BATCH 128
#define XD 128
#define HD 1024
#define ZD 64
#define MROWS (SEQ * BATCH)
#define BH (BATCH * HD)      // 131072
#define B3 (BATCH * 3072)    // 393216

__device__ __forceinline__ f32x4 mfma16(bf16x8 a, bf16x8 b, f32x4 c) {
  return __builtin_amdgcn_mfma_f32_16x16x32_bf16(a, b, c, 0, 0, 0);
}
__device__ __forceinline__ float sigmoidf_(float x) { return 1.f / (1.f + __expf(-x)); }

// A row-major [M][K], B row-major [N][K] (B^T GEMM). A-frag = A[lane&15][(lane>>4)*8+i].
// C/D: col = lane&15, row = (lane>>4)*4 + reg.
template <int MT, int NT>
__device__ __forceinline__ void mma_block(const bf16* __restrict__ a0, size_t aStride,
                                          const bf16* __restrict__ b0, size_t bStride,
                                          int K, f32x4 acc[MT][NT]) {
#pragma unroll 2
  for (int k = 0; k < K; k += 32) {
    bf16x8 af[MT], bfr[NT];
#pragma unroll
    for (int i = 0; i < MT; ++i) af[i] = *(const bf16x8*)(a0 + (size_t)i * aStride + k);
#pragma unroll
    for (int j = 0; j < NT; ++j) bfr[j] = *(const bf16x8*)(b0 + (size_t)j * bStride + k);
#pragma unroll
    for (int i = 0; i < MT; ++i)
#pragma unroll
      for (int j = 0; j < NT; ++j) acc[i][j] = mfma16(af[i], bfr[j], acc[i][j]);
  }
}

// ---------------- fp32 -> bf16 conversion (column slicing for concat splits) --------
__global__ void cvt_k(bf16* __restrict__ dst, const float* __restrict__ src, long n,
                      int cols, int src_ld, int col_off) {
  long i = (long)blockIdx.x * blockDim.x + threadIdx.x;
  long stride = (long)gridDim.x * blockDim.x;
  for (; i < n; i += stride) {
    long row = i / cols;
    int c = (int)(i - row * cols);
    dst[i] = (bf16)src[row * (long)src_ld + col_off + c];
  }
}

// ---------------- generic GEMM (B^T), bf16 or f32 out, bias/add/relu ----------------
struct Epi {
  bf16* C;
  float* Cf;
  const float* bias;
  const bf16* add;
  int relu;
  int ldc;
};

template <int MT, int NT>
__global__ void gemm_bt(const bf16* __restrict__ A, int lda, const bf16* __restrict__ B,
                        int ldb, int M, int N, int K, Epi e) {
  const int lane = threadIdx.x & 63;
  const int r = lane & 15, kb = lane >> 4;
  const int gw = blockIdx.x * (blockDim.x >> 6) + (threadIdx.x >> 6);
  const int nw = gridDim.x * (blockDim.x >> 6);
  const int ntm = M / (16 * MT), ntn = N / (16 * NT);
  for (int task = gw; task < ntm * ntn; task += nw) {
    int mt = task % ntm, nt = task / ntm;
    int m0 = mt * 16 * MT, n0 = nt * 16 * NT;
    f32x4 acc[MT][NT] = {};
    const bf16* a0 = A + (size_t)(m0 + r) * lda + kb * 8;
    const bf16* b0 = B + (size_t)(n0 + r) * ldb + kb * 8;
    mma_block<MT, NT>(a0, (size_t)16 * lda, b0, (size_t)16 * ldb, K, acc);
#pragma unroll
    for (int i = 0; i < MT; ++i)
#pragma unroll
      for (int j = 0; j < NT; ++j)
#pragma unroll
        for (int q = 0; q < 4; ++q) {
          size_t gm = (size_t)m0 + i * 16 + kb * 4 + q;
          int gn = n0 + j * 16 + r;
          float v = acc[i][j][q] + e.bias[gn];
          if (e.add) v += (float)e.add[gm * e.ldc + gn];
          if (e.relu) v = fmaxf(v, 0.f);
          if (e.Cf) e.Cf[gm * e.ldc + gn] = v;
          else e.C[gm * e.ldc + gn] = (bf16)v;
        }
  }
}

// ---------------- the pipelined recurrence (cooperative, 3 grid syncs / step) -------
// Iter t (h = h_{t-1} in H/HB):
//  P1: A: [prior|ench|gh|dhp] = h@WA^T (1536 tasks)   B: dec1_{t-1} (256)   C: phi_x_{t+1} (256)
//  P2: blocks 0..7: meanstd/z/kld/phi_z_t. blocks 8+: E dec2_{t-1}(32) F encx_{t+1}(256) G1 gix_{t+1}(384)
//  P3: H: gi_z_t + GRU update (512)   G2: gix_{t+1} rest (384)
struct LoopP {
  const bf16 *WA, *WB, *WPZ, *WIZ, *WIX, *WXX, *WPX, *WDZ, *WD2, *XBF;
  bf16 *HB, *PT, *ET, *PHIX, *ENCX, *PHIZ, *DHP, *DECH;
  float *H, *GH, *GIX, *KLD, *RPART, *out;
  const float *eps, *x;
  const float *prior_b, *gru_bh, *gru_bi, *pm_b, *ps_b, *em_b, *es_b, *pz_b, *phx_b,
      *enc_b, *dec1_b, *dec2_b;
};

__global__ void __launch_bounds__(512) vrnn_loop(LoopP p) {
  cg::grid_group grid = cg::this_grid();
  const int tid = threadIdx.x;
  const int lane = tid & 63;
  const int wv = tid >> 6;     // 0..7
  const int b = blockIdx.x;    // 0..255
  const int r = lane & 15, kb = lane >> 4;
  const int gw = b * 8 + wv;   // 0..2047

  __shared__ float sm[4][16][64];
  __shared__ bf16 zs[16][64];
  __shared__ float red[8];

  for (int t = 0; t < SEQ; ++t) {
    const int cur = t & 1, oth = cur ^ 1; // oth = (t-1)&1 = (t+1)&1

    // ================= Phase 1 =================
    if (gw < 1536) {
      const int m0 = (gw & 7) * 16, n0 = (gw >> 3) * 32;
      f32x4 acc[1][2] = {};
      const bf16* a0 = p.HB + (size_t)(m0 + r) * HD + kb * 8;
      const bf16* b0 = p.WA + (size_t)(n0 + r) * HD + kb * 8;
      mma_block<1, 2>(a0, 0, b0, (size_t)16 * HD, HD, acc);
#pragma unroll
      for (int j = 0; j < 2; ++j)
#pragma unroll
        for (int q = 0; q < 4; ++q) {
          int gm = m0 + kb * 4 + q, gn = n0 + j * 16 + r;
          float v = acc[0][j][q];
          if (gn < 1024) {
            p.PT[gm * HD + gn] = (bf16)fmaxf(v + p.prior_b[gn], 0.f);
          } else if (gn < 2048) {
            int c = gn - 1024;
            p.ET[gm * HD + c] = (bf16)fmaxf(v + (float)p.ENCX[cur * BH + gm * HD + c], 0.f);
          } else if (gn < 5120) {
            int c = gn - 2048;
            p.GH[gm * 3072 + c] = v + p.gru_bh[c];
          } else {
            int c = gn - 5120;
            p.DHP[cur * BH + gm * HD + c] = (bf16)v;
          }
        }
    } else if (gw < 1792) {
      if (t > 0) { // dec1_{t-1} = relu(phi_z@WDZ^T + dhp + b)
        const int bid = gw - 1536;
        const int m0 = (bid & 7) * 16, n0 = (bid >> 3) * 32;
        f32x4 acc[1][2] = {};
        const bf16* a0 = p.PHIZ + oth * BH + (size_t)(m0 + r) * HD + kb * 8;
        const bf16* b0 = p.WDZ + (size_t)(n0 + r) * HD + kb * 8;
        mma_block<1, 2>(a0, 0, b0, (size_t)16 * HD, HD, acc);
#pragma unroll
        for (int j = 0; j < 2; ++j)
#pragma unroll
          for (int q = 0; q < 4; ++q) {
            int gm = m0 + kb * 4 + q, gn = n0 + j * 16 + r;
            float v = acc[0][j][q] + (float)p.DHP[oth * BH + gm * HD + gn] + p.dec1_b[gn];
            p.DECH[gm * HD + gn] = (bf16)fmaxf(v, 0.f);
          }
      }
    } else {
      if (t < SEQ - 1) { // phi_x_{t+1}
        const int cid = gw - 1792;
        const int m0 = (cid & 7) * 16, n0 = (cid >> 3) * 32;
        f32x4 acc[1][2] = {};
        const bf16* a0 = p.XBF + ((size_t)(t + 1) * BATCH + m0 + r) * XD + kb * 8;
        const bf16* b0 = p.WPX + (size_t)(n0 + r) * XD + kb * 8;
        mma_block<1, 2>(a0, 0, b0, (size_t)16 * XD, XD, acc);
#pragma unroll
        for (int j = 0; j < 2; ++j)
#pragma unroll
          for (int q = 0; q < 4; ++q) {
            int gm = m0 + kb * 4 + q, gn = n0 + j * 16 + r;
            p.PHIX[gm * HD + gn] = (bf16)fmaxf(acc[0][j][q] + p.phx_b[gn], 0.f);
          }
      }
    }
    grid.sync();

    // ================= Phase 2 =================
    if (b < 8) {
      const int m0 = b * 16;
      if (wv < 4) { // (a) [pm|ps|em|es]: 64 cols each
        const bf16* Am = (wv < 2) ? p.PT : p.ET;
        const int n0 = wv * 64;
        f32x4 acc[1][4] = {};
        const bf16* a0 = Am + (size_t)(m0 + r) * HD + kb * 8;
        const bf16* b0 = p.WB + (size_t)(n0 + r) * HD + kb * 8;
        mma_block<1, 4>(a0, 0, b0, (size_t)16 * HD, HD, acc);
        const float* bw = (wv == 0) ? p.pm_b : (wv == 1) ? p.ps_b : (wv == 2) ? p.em_b : p.es_b;
#pragma unroll
        for (int j = 0; j < 4; ++j)
#pragma unroll
          for (int q = 0; q < 4; ++q) sm[wv][kb * 4 + q][j * 16 + r] = acc[0][j][q] + bw[j * 16 + r];
      }
      __syncthreads();
      float kacc = 0.f;
      for (int e = tid; e < 1024; e += 512) { // (b) z + kld
        int row = e >> 6, col = e & 63;
        float pm = sm[0][row][col], ps = sm[1][row][col];
        float em = sm[2][row][col], es = sm[3][row][col];
        float ev = p.eps[((size_t)t * BATCH + m0 + row) * ZD + col];
        zs[row][col] = (bf16)(em + ev * __expf(0.5f * es));
        float dm = em - pm;
        kacc += 1.f + es - dm * dm - __expf(es - ps);
      }
#pragma unroll
      for (int off = 32; off > 0; off >>= 1) kacc += __shfl_down(kacc, off, 64);
      if (lane == 0) red[wv] = kacc;
      __syncthreads();
      if (tid == 0) {
        float s = 0.f;
        for (int i = 0; i < 8; ++i) s += red[i];
        p.KLD[t * 8 + b] = s;
      }
      { // (c) phi_z_t: wave wv owns 128 cols
        const int n0 = wv * 128;
        f32x4 acc[1][8] = {};
        const bf16* a0 = &zs[r][kb * 8];
        const bf16* b0 = p.WPZ + (size_t)(n0 + r) * ZD + kb * 8;
        mma_block<1, 8>(a0, 0, b0, (size_t)16 * ZD, ZD, acc);
#pragma unroll
        for (int j = 0; j < 8; ++j)
#pragma unroll
          for (int q = 0; q < 4; ++q) {
            int gn = n0 + j * 16 + r, gm = m0 + kb * 4 + q;
            p.PHIZ[cur * BH + gm * HD + gn] = (bf16)fmaxf(acc[0][j][q] + p.pz_b[gn], 0.f);
          }
      }
    } else {
      const int vg = wv * 248 + (b - 8); // 0..1983
      if (vg < 32) {
        if (t > 0) { // E: dec2_{t-1} + recon + sigmoid-out
          const int m0 = (vg & 7) * 16, n0 = (vg >> 3) * 32;
          f32x4 acc[1][2] = {};
          const bf16* a0 = p.DECH + (size_t)(m0 + r) * HD + kb * 8;
          const bf16* b0 = p.WD2 + (size_t)(n0 + r) * HD + kb * 8;
          mma_block<1, 2>(a0, 0, b0, (size_t)16 * HD, HD, acc);
          float racc = 0.f;
#pragma unroll
          for (int j = 0; j < 2; ++j)
#pragma unroll
            for (int q = 0; q < 4; ++q) {
              int gm = m0 + kb * 4 + q, gn = n0 + j * 16 + r;
              float l = acc[0][j][q] + p.dec2_b[gn];
              size_t oi = ((size_t)(t - 1) * BATCH + gm) * XD + gn;
              p.out[2 + oi] = sigmoidf_(l);
              float spp = fmaxf(l, 0.f) + log1pf(__expf(-fabsf(l)));
              racc += spp - p.x[oi] * l;
            }
#pragma unroll
          for (int off = 32; off > 0; off >>= 1) racc += __shfl_down(racc, off, 64);
          if (lane == 0) p.RPART[(t - 1) * 32 + vg] = racc;
        }
      } else if (vg < 288) {
        if (t < SEQ - 1) { // F: encx_{t+1} (no relu!)
          const int fid = vg - 32;
          const int m0 = (fid & 7) * 16, n0 = (fid >> 3) * 32;
          f32x4 acc[1][2] = {};
          const bf16* a0 = p.PHIX + (size_t)(m0 + r) * HD + kb * 8;
          const bf16* b0 = p.WXX + (size_t)(n0 + r) * HD + kb * 8;
          mma_block<1, 2>(a0, 0, b0, (size_t)16 * HD, HD, acc);
#pragma unroll
          for (int j = 0; j < 2; ++j)
#pragma unroll
            for (int q = 0; q < 4; ++q) {
              int gm = m0 + kb * 4 + q, gn = n0 + j * 16 + r;
              p.ENCX[oth * BH + gm * HD + gn] = (bf16)(acc[0][j][q] + p.enc_b[gn]);
            }
        }
      } else if (vg < 672) {
        if (t < SEQ - 1) { // G1: gix_{t+1} first 384 tasks
          const int gid = vg - 288;
          const int m0 = (gid & 7) * 16, n0 = (gid >> 3) * 32;
          f32x4 acc[1][2] = {};
          const bf16* a0 = p.PHIX + (size_t)(m0 + r) * HD + kb * 8;
          const bf16* b0 = p.WIX + (size_t)(n0 + r) * HD + kb * 8;
          mma_block<1, 2>(a0, 0, b0, (size_t)16 * HD, HD, acc);
#pragma unroll
          for (int j = 0; j < 2; ++j)
#pragma unroll
            for (int q = 0; q < 4; ++q) {
              int gm = m0 + kb * 4 + q, gn = n0 + j * 16 + r;
              p.GIX[(size_t)oth * B3 + gm * 3072 + gn] = acc[0][j][q] + p.gru_bi[gn];
            }
        }
      }
    }
    grid.sync();

    // ================= Phase 3 =================
    {
      const int vg3 = wv * 256 + b; // 0..2047
      if (vg3 < 512) { // H: gi_z + GRU
        const int m0 = (vg3 & 7) * 16, j0 = (vg3 >> 3) * 16;
        f32x4 acc[1][3] = {};
        const bf16* a0 = p.PHIZ + cur * BH + (size_t)(m0 + r) * HD + kb * 8;
        const bf16* b0 = p.WIZ + (size_t)(j0 + r) * HD + kb * 8;
        mma_block<1, 3>(a0, 0, b0, (size_t)1024 * HD, HD, acc);
#pragma unroll
        for (int q = 0; q < 4; ++q) {
          int gm = m0 + kb * 4 + q, c = j0 + r;
          size_t gb = (size_t)cur * B3 + gm * 3072 + c;
          float ir = acc[0][0][q] + p.GIX[gb];
          float iz = acc[0][1][q] + p.GIX[gb + 1024];
          float in_ = acc[0][2][q] + p.GIX[gb + 2048];
          float hr = p.GH[gm * 3072 + c];
          float hz = p.GH[gm * 3072 + c + 1024];
          float hn = p.GH[gm * 3072 + c + 2048];
          float rr = sigmoidf_(ir + hr);
          float zg = sigmoidf_(iz + hz);
          float nn = tanhf(in_ + rr * hn);
          float hv = p.H[gm * HD + c];
          float hnew = (1.f - zg) * nn + zg * hv;
          p.H[gm * HD + c] = hnew;
          p.HB[gm * HD + c] = (bf16)hnew;
        }
      } else if (vg3 < 896) {
        if (t < SEQ - 1) { // G2: gix_{t+1} remaining 384 tasks
          const int gid = 384 + (vg3 - 512);
          const int m0 = (gid & 7) * 16, n0 = (gid >> 3) * 32;
          f32x4 acc[1][2] = {};
          const bf16* a0 = p.PHIX + (size_t)(m0 + r) * HD + kb * 8;
          const bf16* b0 = p.WIX + (size_t)(n0 + r) * HD + kb * 8;
          mma_block<1, 2>(a0, 0, b0, (size_t)16 * HD, HD, acc);
#pragma unroll
          for (int j = 0; j < 2; ++j)
#pragma unroll
            for (int q = 0; q < 4; ++q) {
              int gm = m0 + kb * 4 + q, gn = n0 + j * 16 + r;
              p.GIX[(size_t)oth * B3 + gm * 3072 + gn] = acc[0][j][q] + p.gru_bi[gn];
            }
        }
      }
    }
    grid.sync();
  }
}

// ---------------- epilogue dec2 for t=255 -------------------------------------------
__global__ void dec2_last(const bf16* __restrict__ A, const bf16* __restrict__ W,
                          const float* __restrict__ x, const float* __restrict__ b2,
                          float* __restrict__ out, float* __restrict__ rpart) {
  const int lane = threadIdx.x & 63;
  const int r = lane & 15, kb = lane >> 4;
  const int w = blockIdx.x * 4 + (threadIdx.x >> 6); // 0..31
  const int m0 = (w & 7) * 16, n0 = (w >> 3) * 32;
  f32x4 acc[1][2] = {};
  const bf16* a0 = A + (size_t)(m0 + r) * HD + kb * 8;
  const bf16* b0 = W + (size_t)(n0 + r) * HD + kb * 8;
  mma_block<1, 2>(a0, 0, b0, (size_t)16 * HD, HD, acc);
  float racc = 0.f;
#pragma unroll
  for (int j = 0; j < 2; ++j)
#pragma unroll
    for (int q = 0; q < 4; ++q) {
      int gm = m0 + kb * 4 + q, gn = n0 + j * 16 + r;
      float l = acc[0][j][q] + b2[gn];
      size_t oi = ((size_t)255 * BATCH + gm) * XD + gn;
      out[2 + oi] = sigmoidf_(l);
      float spp = fmaxf(l, 0.f) + log1pf(__expf(-fabsf(l)));
      racc += spp - x[oi] * l;
    }
#pragma unroll
  for (int off = 32; off > 0; off >>= 1) racc += __shfl_down(racc, off, 64);
  if (lane == 0) rpart[255 * 32 + w] = racc;
}

__global__ void finalize_k(const float* __restrict__ rp, const float* __restrict__ kp,
                           float* __restrict__ out) {
  __shared__ float s[256];
  int tid = threadIdx.x;
  float a = 0.f;
  for (int i = tid; i < 256 * 32; i += 256) a += rp[i];
  s[tid] = a;
  __syncthreads();
  for (int off = 128; off > 0; off >>= 1) {
    if (tid < off) s[tid] += s[tid + off];
    __syncthreads();
  }
  if (tid == 0) out[0] = s[0] / (float)BATCH;
  __syncthreads();
  float bb = 0.f;
  for (int i = tid; i < 2048; i += 256) bb += kp[i];
  s[tid] = bb;
  __syncthreads();
  for (int off = 128; off > 0; off >>= 1) {
    if (tid < off) s[tid] += s[tid + off];
    __syncthreads();
  }
  if (tid == 0) out[1] = -0.5f * s[0] / (float)BATCH;
}

__global__ void sentinel_k(float* out) {
  if (threadIdx.x == 0) { out[0] = 1e9f; out[1] = 1e9f; }
}

// =====================================================================================
extern "C" void kernel_launch(void* const* d_in, const int* in_sizes, int n_in, void* d_out,
                              int out_size, void* d_ws, size_t ws_size, hipStream_t stream) {
  const float* x = (const float*)d_in[0];
  const float* eps = (const float*)d_in[1];
  const float* phi_x_W = (const float*)d_in[2];
  const float* phi_x_b = (const float*)d_in[3];
  const float* enc_W = (const float*)d_in[4];
  const float* enc_b = (const float*)d_in[5];
  const float* enc_mean_W = (const float*)d_in[6];
  const float* enc_mean_b = (const float*)d_in[7];
  const float* enc_std_W = (const float*)d_in[8];
  const float* enc_std_b = (const float*)d_in[9];
  const float* prior_W = (const float*)d_in[10];
  const float* prior_b = (const float*)d_in[11];
  const float* prior_mean_W = (const float*)d_in[12];
  const float* prior_mean_b = (const float*)d_in[13];
  const float* prior_std_W = (const float*)d_in[14];
  const float* prior_std_b = (const float*)d_in[15];
  const float* phi_z_W = (const float*)d_in[16];
  const float* phi_z_b = (const float*)d_in[17];
  const float* dec1_W = (const float*)d_in[18];
  const float* dec1_b = (const float*)d_in[19];
  const float* dec2_W = (const float*)d_in[20];
  const float* dec2_b = (const float*)d_in[21];
  const float* gru_Wi = (const float*)d_in[22];
  const float* gru_Wh = (const float*)d_in[23];
  const float* gru_bi = (const float*)d_in[24];
  const float* gru_bh = (const float*)d_in[25];
  float* out = (float*)d_out;

  char* w = (char*)d_ws;
  auto carve = [&](size_t bytes) {
    char* pp = w;
    w += (bytes + 255) & ~(size_t)255;
    return pp;
  };
  bf16* WA = (bf16*)carve((size_t)6144 * HD * 2);  // [prior_W; enc_Wh; gru_Wh; dec1_Wh]
  bf16* WB = (bf16*)carve((size_t)256 * HD * 2);   // [pm;ps;em;es]
  bf16* WPZ = (bf16*)carve((size_t)HD * ZD * 2);
  bf16* WIZ = (bf16*)carve((size_t)3072 * HD * 2); // gru_Wi[:,1024:]
  bf16* WIX = (bf16*)carve((size_t)3072 * HD * 2); // gru_Wi[:,:1024]
  bf16* WXX = (bf16*)carve((size_t)HD * HD * 2);   // enc_W[:,:1024]
  bf16* WPX = (bf16*)carve((size_t)HD * XD * 2);
  bf16* WDZ = (bf16*)carve((size_t)HD * HD * 2);   // dec1_W[:,:1024]
  bf16* WD2 = (bf16*)carve((size_t)XD * HD * 2);
  bf16* XBF = (bf16*)carve((size_t)MROWS * XD * 2);
  float* H = (float*)carve((size_t)BH * 4);
  bf16* HB = (bf16*)carve((size_t)BH * 2);
  bf16* PT = (bf16*)carve((size_t)BH * 2);
  bf16* ET = (bf16*)carve((size_t)BH * 2);
  float* GH = (float*)carve((size_t)B3 * 4);
  bf16* PHIX = (bf16*)carve((size_t)BH * 2);
  bf16* ENCX = (bf16*)carve((size_t)2 * BH * 2);
  bf16* PHIZ = (bf16*)carve((size_t)2 * BH * 2);
  bf16* DHP = (bf16*)carve((size_t)2 * BH * 2);
  bf16* DECH = (bf16*)carve((size_t)BH * 2);
  float* GIX = (float*)carve((size_t)2 * B3 * 4);
  float* KLD = (float*)carve((size_t)SEQ * 8 * 4);
  float* RPART = (float*)carve((size_t)SEQ * 32 * 4);
  if ((size_t)(w - (char*)d_ws) > ws_size) {
    sentinel_k<<<1, 64, 0, stream>>>(out);
    return;
  }

  auto cvt = [&](bf16* dst, const float* src, long n, int cols, int ld, int off) {
    int grid = (int)std::min((n + 255) / 256, (long)2048);
    cvt_k<<<grid, 256, 0, stream>>>(dst, src, n, cols, ld, off);
  };
  cvt(WA, prior_W, (long)HD * HD, HD, HD, 0);
  cvt(WA + (size_t)HD * HD, enc_W, (long)HD * HD, HD, 2 * HD, HD);
  cvt(WA + (size_t)2048 * HD, gru_Wh, (long)3072 * HD, HD, HD, 0);
  cvt(WA + (size_t)5120 * HD, dec1_W, (long)HD * HD, HD, 2 * HD, HD);
  cvt(WB, prior_mean_W, (long)ZD * HD, HD, HD, 0);
  cvt(WB + (size_t)64 * HD, prior_std_W, (long)ZD * HD, HD, HD, 0);
  cvt(WB + (size_t)128 * HD, enc_mean_W, (long)ZD * HD, HD, HD, 0);
  cvt(WB + (size_t)192 * HD, enc_std_W, (long)ZD * HD, HD, HD, 0);
  cvt(WPZ, phi_z_W, (long)HD * ZD, ZD, ZD, 0);
  cvt(WIZ, gru_Wi, (long)3072 * HD, HD, 2 * HD, HD);
  cvt(WIX, gru_Wi, (long)3072 * HD, HD, 2 * HD, 0);
  cvt(WXX, enc_W, (long)HD * HD, HD, 2 * HD, 0);
  cvt(WPX, phi_x_W, (long)HD * XD, XD, XD, 0);
  cvt(WDZ, dec1_W, (long)HD * HD, HD, 2 * HD, 0);
  cvt(WD2, dec2_W, (long)XD * HD, HD, HD, 0);
  cvt(XBF, x, (long)MROWS * XD, XD, XD, 0);

  hipMemsetAsync(H, 0, (size_t)BH * 4, stream);
  hipMemsetAsync(HB, 0, (size_t)BH * 2, stream);

  // prologue: phi_x_0 -> encx_0, gix_0 (slot 0)
  Epi e1{PHIX, nullptr, phi_x_b, nullptr, 1, HD};
  gemm_bt<2, 2><<<32, 256, 0, stream>>>(XBF, XD, WPX, XD, BATCH, HD, XD, e1);
  Epi e2{ENCX, nullptr, enc_b, nullptr, 0, HD};
  gemm_bt<2, 2><<<32, 256, 0, stream>>>(PHIX, HD, WXX, HD, BATCH, HD, HD, e2);
  Epi e3{nullptr, GIX, gru_bi, nullptr, 0, 3072};
  gemm_bt<2, 2><<<96, 256, 0, stream>>>(PHIX, HD, WIX, HD, BATCH, 3072, HD, e3);

  LoopP lp;
  lp.WA = WA; lp.WB = WB; lp.WPZ = WPZ; lp.WIZ = WIZ; lp.WIX = WIX; lp.WXX = WXX;
  lp.WPX = WPX; lp.WDZ = WDZ; lp.WD2 = WD2; lp.XBF = XBF;
  lp.HB = HB; lp.PT = PT; lp.ET = ET; lp.PHIX = PHIX; lp.ENCX = ENCX; lp.PHIZ = PHIZ;
  lp.DHP = DHP; lp.DECH = DECH;
  lp.H = H; lp.GH = GH; lp.GIX = GIX; lp.KLD = KLD; lp.RPART = RPART; lp.out = out;
  lp.eps = eps; lp.x = x;
  lp.prior_b = prior_b; lp.gru_bh = gru_bh; lp.gru_bi = gru_bi;
  lp.pm_b = prior_mean_b; lp.ps_b = prior_std_b; lp.em_b = enc_mean_b; lp.es_b = enc_std_b;
  lp.pz_b = phi_z_b; lp.phx_b = phi_x_b; lp.enc_b = enc_b; lp.dec1_b = dec1_b;
  lp.dec2_b = dec2_b;
  void* args[] = {&lp};
  hipLaunchCooperativeKernel(vrnn_loop, dim3(256), dim3(512), args, 0u, stream);

  // epilogue: dec1_255 (slots t=255 -> 1), dec2_255, losses
  Epi e4{DECH, nullptr, dec1_b, DHP + (size_t)1 * BH, 1, HD};
  gemm_bt<2, 2><<<32, 256, 0, stream>>>(PHIZ + (size_t)1 * BH, HD, WDZ, HD, BATCH, HD, HD, e4);
  dec2_last<<<8, 256, 0, stream>>>(DECH, WD2, x, dec2_b, out, RPART);
  finalize_k<<<1, 256, 0, stream>>>(RPART, KLD, out);
}

// Round 3
// 37130.637 us; speedup vs baseline: 1.2306x; 1.2306x over previous
//
#include <hip/hip_runtime.h>
#include <hip/hip_cooperative_groups.h>
#include <algorithm>

namespace cg = cooperative_groups;

typedef __bf16 bf16;
typedef __bf16 bf16x8 __attribute__((ext_vector_type(8)));
typedef float f32x4 __attribute__((ext_vector_type(4)));

// SEQ=256, B=128, XD=128, HD=1024, ZD=64
#define SEQ 256
#define BATCH 128
#define XD 128
#define HD 1024
#define ZD 64
#define MROWS (SEQ * BATCH)
#define BH (BATCH * HD)   // 131072
#define B3 (BATCH * 3072) // 393216
#define DYN_LDS 149824

__device__ __forceinline__ f32x4 mfma16(bf16x8 a, bf16x8 b, f32x4 c) {
  return __builtin_amdgcn_mfma_f32_16x16x32_bf16(a, b, c, 0, 0, 0);
}
__device__ __forceinline__ float sigmoidf_(float x) { return 1.f / (1.f + __expf(-x)); }

// ---------- generic mma (global A, global B) for prologue/tail kernels --------------
template <int MT, int NT>
__device__ __forceinline__ void mma_block(const bf16* __restrict__ a0, size_t aStride,
                                          const bf16* __restrict__ b0, size_t bStride,
                                          int K, f32x4 acc[MT][NT]) {
#pragma unroll 2
  for (int k = 0; k < K; k += 32) {
    bf16x8 af[MT], bfr[NT];
#pragma unroll
    for (int i = 0; i < MT; ++i) af[i] = *(const bf16x8*)(a0 + (size_t)i * aStride + k);
#pragma unroll
    for (int j = 0; j < NT; ++j) bfr[j] = *(const bf16x8*)(b0 + (size_t)j * bStride + k);
#pragma unroll
    for (int i = 0; i < MT; ++i)
#pragma unroll
      for (int j = 0; j < NT; ++j) acc[i][j] = mfma16(af[i], bfr[j], acc[i][j]);
  }
}

// ---------------- fp32 -> bf16 conversion (column slicing for concat splits) --------
__global__ void cvt_k(bf16* __restrict__ dst, const float* __restrict__ src, long n,
                      int cols, int src_ld, int col_off) {
  long i = (long)blockIdx.x * blockDim.x + threadIdx.x;
  long stride = (long)gridDim.x * blockDim.x;
  for (; i < n; i += stride) {
    long row = i / cols;
    int c = (int)(i - row * cols);
    dst[i] = (bf16)src[row * (long)src_ld + col_off + c];
  }
}

// ---------------- generic GEMM (B^T) for prologue ----------------------------------
struct Epi {
  bf16* C;
  float* Cf;
  const float* bias;
  const bf16* add;
  int relu;
  int ldc;
};

template <int MT, int NT>
__global__ void gemm_bt(const bf16* __restrict__ A, int lda, const bf16* __restrict__ B,
                        int ldb, int M, int N, int K, Epi e) {
  const int lane = threadIdx.x & 63;
  const int r = lane & 15, kb = lane >> 4;
  const int gw = blockIdx.x * (blockDim.x >> 6) + (threadIdx.x >> 6);
  const int nw = gridDim.x * (blockDim.x >> 6);
  const int ntm = M / (16 * MT), ntn = N / (16 * NT);
  for (int task = gw; task < ntm * ntn; task += nw) {
    int mt = task % ntm, nt = task / ntm;
    int m0 = mt * 16 * MT, n0 = nt * 16 * NT;
    f32x4 acc[MT][NT] = {};
    const bf16* a0 = A + (size_t)(m0 + r) * lda + kb * 8;
    const bf16* b0 = B + (size_t)(n0 + r) * ldb + kb * 8;
    mma_block<MT, NT>(a0, (size_t)16 * lda, b0, (size_t)16 * ldb, K, acc);
#pragma unroll
    for (int i = 0; i < MT; ++i)
#pragma unroll
      for (int j = 0; j < NT; ++j)
#pragma unroll
        for (int q = 0; q < 4; ++q) {
          size_t gm = (size_t)m0 + i * 16 + kb * 4 + q;
          int gn = n0 + j * 16 + r;
          float v = acc[i][j][q] + e.bias[gn];
          if (e.add) v += (float)e.add[gm * e.ldc + gn];
          if (e.relu) v = fmaxf(v, 0.f);
          if (e.Cf) e.Cf[gm * e.ldc + gn] = v;
          else e.C[gm * e.ldc + gn] = (bf16)v;
        }
  }
}

// ===================== the LDS-weight-pinned recurrence ==============================
struct LoopP {
  const bf16 *WA, *WB, *WPZ, *WIZ, *WIX, *WXX, *WPX, *WDZ, *WD2, *XBF;
  bf16 *HB, *PT, *ET, *PHIX, *ENCX, *PHIZ, *DHP, *DECH;
  float *H, *GH, *GIX, *KLD, *RPART, *out;
  const float *eps, *x;
  const float *prior_b, *gru_bh, *gru_bi, *pm_b, *ps_b, *em_b, *es_b, *pz_b, *phx_b,
      *enc_b, *dec1_b, *dec2_b;
};

// stage 16 rows x K=1024 into k-major LDS unit: [128 kg][16 row][16B]
__device__ __forceinline__ void stage1024(char* lds, int off, const bf16* src) {
  for (int c = threadIdx.x; c < 2048; c += 512) {
    int kg = c & 127, rr = c >> 7;
    *(float4*)(lds + off + (((kg << 4) + rr) << 4)) =
        *(const float4*)(src + (size_t)rr * 1024 + kg * 8);
  }
}

template <int KK>
__device__ __forceinline__ void load_af(bf16x8* af, const bf16* A, int row, int lda, int k0,
                                        int kb) {
#pragma unroll
  for (int kk = 0; kk < KK; ++kk)
    af[kk] = *(const bf16x8*)(A + (size_t)row * lda + k0 + kk * 32 + kb * 8);
}

__device__ __forceinline__ f32x4 unit_mma32(const bf16x8* af, const char* slab, int kb, int r) {
  f32x4 acc = {};
#pragma unroll
  for (int kk = 0; kk < 32; ++kk)
    acc = mfma16(af[kk], *(const bf16x8*)(slab + ((((kk * 4 + kb) << 4) + r) << 4)), acc);
  return acc;
}

__global__ void __launch_bounds__(512, 2) vrnn_loop(LoopP p) {
  extern __shared__ char lds[];
  cg::grid_group grid = cg::this_grid();
  const int tid = threadIdx.x, lane = tid & 63, wv = tid >> 6;
  const int r = lane & 15, kb = lane >> 4;
  const int b = blockIdx.x;
  const bool special = b < 8;
  const int q = b - 8;

  // ----- static unit assignment (see analysis) -----
  int p1n = 0, p1uid0 = 0;
  bool p1wdz = false;
  int p2n = 0, p2kind = -1, p2id0 = 0; // 0 dhp, 1 wxx, 2 wixa, 3 wd2
  int p3kind = 0, p3id = 0;            // 1 fused giz, 2 wixb
  int wpxn = 0, wpxid0 = 0;
  if (!special) {
    if (q < 64) {
      p1n = 1; p1uid0 = q; p3kind = 1; p3id = q;
    } else if (q < 96) {
      p1n = 2; p1uid0 = 384 + 2 * (q - 64); p1wdz = true;
      p2n = 1; p2kind = 2; p2id0 = q - 64;
    } else if (q < 224) {
      p1n = 2; p1uid0 = 64 + 2 * (q - 96);
      if (q < 128) { p2n = 2; p2kind = 0; p2id0 = 2 * (q - 96); }
      else if (q < 144) { p2n = 2; p2kind = 1; p2id0 = 2 * (q - 128); }
      else if (q < 176) { p2n = 1; p2kind = 1; p2id0 = 32 + (q - 144); }
      else { p2n = 1; p2kind = 2; p2id0 = 32 + (q - 176); }
      if (q >= 144) { p3kind = 2; p3id = q - 144; }
    } else if (q < 240) {
      p2n = 1; p2kind = 2; p2id0 = 32 + (q - 176);
      p3kind = 2; p3id = q - 144;
    } else {
      p2n = 1; p2kind = 3; p2id0 = q - 240;
      wpxn = 8; wpxid0 = 8 * (q - 240);
    }
  }
  const int p1off = 0;
  const int p2off = (q >= 224) ? 0 : 65536;
  const int p3off = (q < 64 || q >= 224) ? 32768 : 98304;
  const int scoff = 131072;
  const int wpxoff = 32768;

  // ----- one-time staging of weights into LDS -----
  if (special) {
    for (int c = tid; c < 8192; c += 512) {
      int kg = c & 7, rr = (c >> 3) & 15, u = c >> 7;
      *(float4*)(lds + u * 2048 + (((kg << 4) + rr) << 4)) =
          *(const float4*)(p.WPZ + (size_t)(u * 16 + rr) * 64 + kg * 8);
    }
  } else {
    for (int u = 0; u < p1n; ++u) {
      int uid = p1uid0 + u;
      const bf16* src = (uid < 384) ? p.WA + (size_t)uid * 16 * 1024
                                    : p.WDZ + (size_t)(uid - 384) * 16 * 1024;
      stage1024(lds, p1off + u * 32768, src);
    }
    for (int u = 0; u < p2n; ++u) {
      int id = p2id0 + u;
      const bf16* src = (p2kind == 0) ? p.WA + (size_t)(5120 + id * 16) * 1024
                      : (p2kind == 1) ? p.WXX + (size_t)id * 16 * 1024
                      : (p2kind == 2) ? p.WIX + (size_t)id * 16 * 1024
                                      : p.WD2 + (size_t)id * 16 * 1024;
      stage1024(lds, p2off + u * 32768, src);
    }
    if (p3kind == 1)
      for (int g = 0; g < 3; ++g)
        stage1024(lds, p3off + g * 32768, p.WIZ + (size_t)(g * 1024 + p3id * 16) * 1024);
    if (p3kind == 2) stage1024(lds, p3off, p.WIX + (size_t)(1536 + p3id * 16) * 1024);
    for (int u = 0; u < wpxn; ++u)
      if (tid < 256) {
        int kg = tid & 15, rr = tid >> 4;
        *(float4*)(lds + wpxoff + u * 4096 + (((kg << 4) + rr) << 4)) =
            *(const float4*)(p.WPX + (size_t)((wpxid0 + u) * 16 + rr) * 128 + kg * 8);
      }
  }
  __syncthreads();

  for (int t = 0; t < SEQ; ++t) {
    const int cur = t & 1, oth = cur ^ 1;

    // ================= Phase 1: prior|ench|gh (A=h), dec1 (A=phiz_{t-1}), phix_{t+1}
    if (!special) {
      if (p1n && (!p1wdz || t > 0)) {
        const bf16* A = p1wdz ? p.PHIZ + (size_t)oth * BH : p.HB;
        bf16x8 af[32];
        load_af<32>(af, A, wv * 16 + r, 1024, 0, kb);
        for (int u = 0; u < p1n; ++u) {
          f32x4 acc = unit_mma32(af, lds + p1off + u * 32768, kb, r);
          int uid = p1uid0 + u;
          int gn = uid * 16 + r;
#pragma unroll
          for (int qq = 0; qq < 4; ++qq) {
            int gm = wv * 16 + kb * 4 + qq;
            float v = acc[qq];
            if (uid < 64) {
              p.PT[gm * HD + gn] = (bf16)fmaxf(v + p.prior_b[gn], 0.f);
            } else if (uid < 128) {
              int c = gn - 1024;
              p.ET[gm * HD + c] =
                  (bf16)fmaxf(v + (float)p.ENCX[(size_t)cur * BH + gm * HD + c], 0.f);
            } else if (uid < 320) {
              int c = gn - 2048;
              p.GH[gm * 3072 + c] = v + p.gru_bh[c];
            } else { // wdz (dec1 for t-1)
              int c = (uid - 384) * 16 + r;
              float vv = v + (float)p.DHP[(size_t)oth * BH + gm * HD + c] + p.dec1_b[c];
              p.DECH[gm * HD + c] = (bf16)fmaxf(vv, 0.f);
            }
          }
        }
      }
      if (wpxn && t < SEQ - 1) { // phi_x_{t+1}, K=128
        bf16x8 af2[4];
        load_af<4>(af2, p.XBF + (size_t)(t + 1) * BATCH * XD, wv * 16 + r, 128, 0, kb);
        for (int u = 0; u < 8; ++u) {
          f32x4 acc = {};
#pragma unroll
          for (int kk = 0; kk < 4; ++kk)
            acc = mfma16(af2[kk],
                         *(const bf16x8*)(lds + wpxoff + u * 4096 +
                                          ((((kk * 4 + kb) << 4) + r) << 4)),
                         acc);
          int gn = (wpxid0 + u) * 16 + r;
#pragma unroll
          for (int qq = 0; qq < 4; ++qq) {
            int gm = wv * 16 + kb * 4 + qq;
            p.PHIX[gm * HD + gn] = (bf16)fmaxf(acc[qq] + p.phx_b[gn], 0.f);
          }
        }
      }
    }
    grid.sync();

    // ================= Phase 2: special meanstd/z/kld/phiz; dhp/wxx/wixa/wd2
    if (special) {
      const int s = b, m0 = s * 16;
      const int mat = wv & 3, half = wv >> 2;
      float* sm = (float*)(lds + 131072); // [4][16][64]
      bf16* zs = (bf16*)(lds + 147456);   // [16][72]
      float* red = (float*)(lds + 149760);
      {
        const bf16* A = (mat < 2) ? p.PT : p.ET;
        bf16x8 af[32];
        load_af<32>(af, A, m0 + r, 1024, 0, kb);
        const float* bw = mat == 0 ? p.pm_b : mat == 1 ? p.ps_b : mat == 2 ? p.em_b : p.es_b;
#pragma unroll 1
        for (int nt = 0; nt < 2; ++nt) {
          int colb = half * 32 + nt * 16;
          f32x4 acc = {};
#pragma unroll
          for (int kk = 0; kk < 32; ++kk)
            acc = mfma16(af[kk],
                         *(const bf16x8*)(p.WB + (size_t)(mat * 64 + colb + r) * 1024 +
                                          kk * 32 + kb * 8),
                         acc);
#pragma unroll
          for (int qq = 0; qq < 4; ++qq)
            sm[mat * 1024 + (kb * 4 + qq) * 64 + colb + r] = acc[qq] + bw[colb + r];
        }
      }
      __syncthreads();
      float kacc = 0.f;
      for (int e = tid; e < 1024; e += 512) {
        int row = e >> 6, col = e & 63;
        float pm = sm[row * 64 + col], ps = sm[1024 + row * 64 + col];
        float em = sm[2048 + row * 64 + col], es = sm[3072 + row * 64 + col];
        float ev = p.eps[((size_t)t * BATCH + m0 + row) * ZD + col];
        zs[row * 72 + col] = (bf16)(em + ev * __expf(0.5f * es));
        float dm = em - pm;
        kacc += 1.f + es - dm * dm - __expf(es - ps);
      }
#pragma unroll
      for (int off = 32; off; off >>= 1) kacc += __shfl_down(kacc, off, 64);
      if (lane == 0) red[wv] = kacc;
      __syncthreads();
      if (tid == 0) {
        float ss = 0.f;
        for (int i = 0; i < 8; ++i) ss += red[i];
        p.KLD[t * 8 + s] = ss;
      }
      // phiz: A = zs (LDS), B = WPZ (LDS), N=1024 over 8 waves
      bf16x8 afz[2];
      afz[0] = *(const bf16x8*)(zs + r * 72 + kb * 8);
      afz[1] = *(const bf16x8*)(zs + r * 72 + 32 + kb * 8);
#pragma unroll 1
      for (int j = 0; j < 8; ++j) {
        int u = wv * 8 + j;
        f32x4 acc = {};
#pragma unroll
        for (int kk = 0; kk < 2; ++kk)
          acc = mfma16(afz[kk],
                       *(const bf16x8*)(lds + u * 2048 + ((((kk * 4 + kb) << 4) + r) << 4)),
                       acc);
        int gn = u * 16 + r;
#pragma unroll
        for (int qq = 0; qq < 4; ++qq) {
          int gm = m0 + kb * 4 + qq;
          p.PHIZ[(size_t)cur * BH + gm * HD + gn] = (bf16)fmaxf(acc[qq] + p.pz_b[gn], 0.f);
        }
      }
    } else if (p2n) {
      bool go = (p2kind == 0) || (p2kind == 3 ? (t > 0) : (t < SEQ - 1));
      if (go) {
        const bf16* A = (p2kind == 0) ? p.HB : (p2kind == 3) ? p.DECH : p.PHIX;
        bf16x8 af[32];
        load_af<32>(af, A, wv * 16 + r, 1024, 0, kb);
        float racc = 0.f;
        for (int u = 0; u < p2n; ++u) {
          f32x4 acc = unit_mma32(af, lds + p2off + u * 32768, kb, r);
          int id = p2id0 + u;
          int c = id * 16 + r;
#pragma unroll
          for (int qq = 0; qq < 4; ++qq) {
            int gm = wv * 16 + kb * 4 + qq;
            if (p2kind == 0) {
              p.DHP[(size_t)cur * BH + gm * HD + c] = (bf16)acc[qq];
            } else if (p2kind == 1) {
              p.ENCX[(size_t)oth * BH + gm * HD + c] = (bf16)(acc[qq] + p.enc_b[c]);
            } else if (p2kind == 2) {
              p.GIX[(size_t)oth * B3 + gm * 3072 + c] = acc[qq] + p.gru_bi[c];
            } else { // wd2: dec2 for t-1 + recon + sigmoid out
              float l = acc[qq] + p.dec2_b[c];
              size_t oi = ((size_t)(t - 1) * BATCH + gm) * XD + c;
              p.out[2 + oi] = sigmoidf_(l);
              float spp = fmaxf(l, 0.f) + log1pf(__expf(-fabsf(l)));
              racc += spp - p.x[oi] * l;
            }
          }
        }
        if (p2kind == 3) {
#pragma unroll
          for (int off = 32; off; off >>= 1) racc += __shfl_down(racc, off, 64);
          if (lane == 0) p.RPART[(t - 1) * 64 + p2id0 * 8 + wv] = racc;
        }
      }
    }
    grid.sync();

    // ================= Phase 3: fused giz+GRU (K-split), wixb
    if (!special) {
      if (p3kind == 1) {
        const int khalf = wv >> 2;
        float* sc = (float*)(lds + scoff); // [4][3][256]
#pragma unroll 1
        for (int pass = 0; pass < 2; ++pass) {
          int mt = (wv & 3) + 4 * pass;
          bf16x8 af[16];
          load_af<16>(af, p.PHIZ + (size_t)cur * BH, mt * 16 + r, 1024, khalf * 512, kb);
          f32x4 a3[3] = {};
#pragma unroll
          for (int kk = 0; kk < 16; ++kk) {
            bf16x8 a = af[kk];
#pragma unroll
            for (int g = 0; g < 3; ++g)
              a3[g] = mfma16(a,
                             *(const bf16x8*)(lds + p3off + g * 32768 +
                                              (((((khalf * 16 + kk) * 4 + kb) << 4) + r) << 4)),
                             a3[g]);
          }
          if (khalf) {
#pragma unroll
            for (int g = 0; g < 3; ++g)
#pragma unroll
              for (int qq = 0; qq < 4; ++qq)
                sc[((wv & 3) * 3 + g) * 256 + (kb * 4 + qq) * 16 + r] = a3[g][qq];
          }
          __syncthreads();
          if (!khalf) {
            int c = p3id * 16 + r;
#pragma unroll
            for (int qq = 0; qq < 4; ++qq) {
              int gm = mt * 16 + kb * 4 + qq;
              int si = (kb * 4 + qq) * 16 + r;
              float ir = a3[0][qq] + sc[((wv & 3) * 3 + 0) * 256 + si] +
                         p.GIX[(size_t)cur * B3 + gm * 3072 + c];
              float iz = a3[1][qq] + sc[((wv & 3) * 3 + 1) * 256 + si] +
                         p.GIX[(size_t)cur * B3 + gm * 3072 + c + 1024];
              float in_ = a3[2][qq] + sc[((wv & 3) * 3 + 2) * 256 + si] +
                          p.GIX[(size_t)cur * B3 + gm * 3072 + c + 2048];
              float hr = p.GH[gm * 3072 + c], hz = p.GH[gm * 3072 + c + 1024],
                    hn = p.GH[gm * 3072 + c + 2048];
              float rr2 = sigmoidf_(ir + hr), zg = sigmoidf_(iz + hz);
              float nn = tanhf(in_ + rr2 * hn);
              float hv = p.H[gm * HD + c];
              float hnew = (1.f - zg) * nn + zg * hv;
              p.H[gm * HD + c] = hnew;
              p.HB[gm * HD + c] = (bf16)hnew;
            }
          }
          __syncthreads();
        }
      } else if (p3kind == 2 && t < SEQ - 1) {
        bf16x8 af[32];
        load_af<32>(af, p.PHIX, wv * 16 + r, 1024, 0, kb);
        f32x4 acc = unit_mma32(af, lds + p3off, kb, r);
        int c = 1536 + p3id * 16 + r;
#pragma unroll
        for (int qq = 0; qq < 4; ++qq) {
          int gm = wv * 16 + kb * 4 + qq;
          p.GIX[(size_t)oth * B3 + gm * 3072 + c] = acc[qq] + p.gru_bi[c];
        }
      }
    }
    grid.sync();
  }
}

// ---------------- epilogue dec2 for t=255 -------------------------------------------
__global__ void dec2_last(const bf16* __restrict__ A, const bf16* __restrict__ W,
                          const float* __restrict__ x, const float* __restrict__ b2,
                          float* __restrict__ out, float* __restrict__ rpart) {
  const int lane = threadIdx.x & 63;
  const int r = lane & 15, kb = lane >> 4;
  const int w = blockIdx.x * 4 + (threadIdx.x >> 6); // 0..63
  const int m0 = (w & 7) * 16, n0 = (w >> 3) * 16;
  f32x4 acc[1][1] = {};
  const bf16* a0 = A + (size_t)(m0 + r) * HD + kb * 8;
  const bf16* b0 = W + (size_t)(n0 + r) * HD + kb * 8;
  mma_block<1, 1>(a0, 0, b0, (size_t)16 * HD, HD, acc);
  float racc = 0.f;
#pragma unroll
  for (int q = 0; q < 4; ++q) {
    int gm = m0 + kb * 4 + q, gn = n0 + r;
    float l = acc[0][0][q] + b2[gn];
    size_t oi = ((size_t)255 * BATCH + gm) * XD + gn;
    out[2 + oi] = sigmoidf_(l);
    float spp = fmaxf(l, 0.f) + log1pf(__expf(-fabsf(l)));
    racc += spp - x[oi] * l;
  }
#pragma unroll
  for (int off = 32; off; off >>= 1) racc += __shfl_down(racc, off, 64);
  if (lane == 0) rpart[255 * 64 + w] = racc;
}

__global__ void finalize_k(const float* __restrict__ rp, const float* __restrict__ kp,
                           float* __restrict__ out) {
  __shared__ float s[256];
  int tid = threadIdx.x;
  float a = 0.f;
  for (int i = tid; i < 256 * 64; i += 256) a += rp[i];
  s[tid] = a;
  __syncthreads();
  for (int off = 128; off > 0; off >>= 1) {
    if (tid < off) s[tid] += s[tid + off];
    __syncthreads();
  }
  if (tid == 0) out[0] = s[0] / (float)BATCH;
  __syncthreads();
  float bb = 0.f;
  for (int i = tid; i < 2048; i += 256) bb += kp[i];
  s[tid] = bb;
  __syncthreads();
  for (int off = 128; off > 0; off >>= 1) {
    if (tid < off) s[tid] += s[tid + off];
    __syncthreads();
  }
  if (tid == 0) out[1] = -0.5f * s[0] / (float)BATCH;
}

__global__ void sentinel_k(float* out) {
  if (threadIdx.x == 0) { out[0] = 1e9f; out[1] = 1e9f; }
}

// =====================================================================================
extern "C" void kernel_launch(void* const* d_in, const int* in_sizes, int n_in, void* d_out,
                              int out_size, void* d_ws, size_t ws_size, hipStream_t stream) {
  const float* x = (const float*)d_in[0];
  const float* eps = (const float*)d_in[1];
  const float* phi_x_W = (const float*)d_in[2];
  const float* phi_x_b = (const float*)d_in[3];
  const float* enc_W = (const float*)d_in[4];
  const float* enc_b = (const float*)d_in[5];
  const float* enc_mean_W = (const float*)d_in[6];
  const float* enc_mean_b = (const float*)d_in[7];
  const float* enc_std_W = (const float*)d_in[8];
  const float* enc_std_b = (const float*)d_in[9];
  const float* prior_W = (const float*)d_in[10];
  const float* prior_b = (const float*)d_in[11];
  const float* prior_mean_W = (const float*)d_in[12];
  const float* prior_mean_b = (const float*)d_in[13];
  const float* prior_std_W = (const float*)d_in[14];
  const float* prior_std_b = (const float*)d_in[15];
  const float* phi_z_W = (const float*)d_in[16];
  const float* phi_z_b = (const float*)d_in[17];
  const float* dec1_W = (const float*)d_in[18];
  const float* dec1_b = (const float*)d_in[19];
  const float* dec2_W = (const float*)d_in[20];
  const float* dec2_b = (const float*)d_in[21];
  const float* gru_Wi = (const float*)d_in[22];
  const float* gru_Wh = (const float*)d_in[23];
  const float* gru_bi = (const float*)d_in[24];
  const float* gru_bh = (const float*)d_in[25];
  float* out = (float*)d_out;

  char* w = (char*)d_ws;
  auto carve = [&](size_t bytes) {
    char* pp = w;
    w += (bytes + 255) & ~(size_t)255;
    return pp;
  };
  bf16* WA = (bf16*)carve((size_t)6144 * HD * 2);  // [prior;ench;gh;dhp] row-major [.][1024]
  bf16* WB = (bf16*)carve((size_t)256 * HD * 2);   // [pm;ps;em;es]
  bf16* WPZ = (bf16*)carve((size_t)HD * ZD * 2);
  bf16* WIZ = (bf16*)carve((size_t)3072 * HD * 2); // gru_Wi[:,1024:]
  bf16* WIX = (bf16*)carve((size_t)3072 * HD * 2); // gru_Wi[:,:1024]
  bf16* WXX = (bf16*)carve((size_t)HD * HD * 2);   // enc_W[:,:1024]
  bf16* WPX = (bf16*)carve((size_t)HD * XD * 2);
  bf16* WDZ = (bf16*)carve((size_t)HD * HD * 2);   // dec1_W[:,:1024]
  bf16* WD2 = (bf16*)carve((size_t)XD * HD * 2);
  bf16* XBF = (bf16*)carve((size_t)MROWS * XD * 2);
  float* H = (float*)carve((size_t)BH * 4);
  bf16* HB = (bf16*)carve((size_t)BH * 2);
  bf16* PT = (bf16*)carve((size_t)BH * 2);
  bf16* ET = (bf16*)carve((size_t)BH * 2);
  float* GH = (float*)carve((size_t)B3 * 4);
  bf16* PHIX = (bf16*)carve((size_t)BH * 2);
  bf16* ENCX = (bf16*)carve((size_t)2 * BH * 2);
  bf16* PHIZ = (bf16*)carve((size_t)2 * BH * 2);
  bf16* DHP = (bf16*)carve((size_t)2 * BH * 2);
  bf16* DECH = (bf16*)carve((size_t)BH * 2);
  float* GIX = (float*)carve((size_t)2 * B3 * 4);
  float* KLD = (float*)carve((size_t)SEQ * 8 * 4);
  float* RPART = (float*)carve((size_t)SEQ * 64 * 4);
  if ((size_t)(w - (char*)d_ws) > ws_size) {
    sentinel_k<<<1, 64, 0, stream>>>(out);
    return;
  }

  auto cvt = [&](bf16* dst, const float* src, long n, int cols, int ld, int off) {
    int grid = (int)std::min((n + 255) / 256, (long)2048);
    cvt_k<<<grid, 256, 0, stream>>>(dst, src, n, cols, ld, off);
  };
  cvt(WA, prior_W, (long)HD * HD, HD, HD, 0);
  cvt(WA + (size_t)HD * HD, enc_W, (long)HD * HD, HD, 2 * HD, HD);
  cvt(WA + (size_t)2048 * HD, gru_Wh, (long)3072 * HD, HD, HD, 0);
  cvt(WA + (size_t)5120 * HD, dec1_W, (long)HD * HD, HD, 2 * HD, HD);
  cvt(WB, prior_mean_W, (long)ZD * HD, HD, HD, 0);
  cvt(WB + (size_t)64 * HD, prior_std_W, (long)ZD * HD, HD, HD, 0);
  cvt(WB + (size_t)128 * HD, enc_mean_W, (long)ZD * HD, HD, HD, 0);
  cvt(WB + (size_t)192 * HD, enc_std_W, (long)ZD * HD, HD, HD, 0);
  cvt(WPZ, phi_z_W, (long)HD * ZD, ZD, ZD, 0);
  cvt(WIZ, gru_Wi, (long)3072 * HD, HD, 2 * HD, HD);
  cvt(WIX, gru_Wi, (long)3072 * HD, HD, 2 * HD, 0);
  cvt(WXX, enc_W, (long)HD * HD, HD, 2 * HD, 0);
  cvt(WPX, phi_x_W, (long)HD * XD, XD, XD, 0);
  cvt(WDZ, dec1_W, (long)HD * HD, HD, 2 * HD, 0);
  cvt(WD2, dec2_W, (long)XD * HD, HD, HD, 0);
  cvt(XBF, x, (long)MROWS * XD, XD, XD, 0);

  hipMemsetAsync(H, 0, (size_t)BH * 4, stream);
  hipMemsetAsync(HB, 0, (size_t)BH * 2, stream);

  // prologue: phi_x_0 -> encx_0, gix_0 (slot 0)
  Epi e1{PHIX, nullptr, phi_x_b, nullptr, 1, HD};
  gemm_bt<2, 2><<<32, 256, 0, stream>>>(XBF, XD, WPX, XD, BATCH, HD, XD, e1);
  Epi e2{ENCX, nullptr, enc_b, nullptr, 0, HD};
  gemm_bt<2, 2><<<32, 256, 0, stream>>>(PHIX, HD, WXX, HD, BATCH, HD, HD, e2);
  Epi e3{nullptr, GIX, gru_bi, nullptr, 0, 3072};
  gemm_bt<2, 2><<<96, 256, 0, stream>>>(PHIX, HD, WIX, HD, BATCH, 3072, HD, e3);

  LoopP lp;
  lp.WA = WA; lp.WB = WB; lp.WPZ = WPZ; lp.WIZ = WIZ; lp.WIX = WIX; lp.WXX = WXX;
  lp.WPX = WPX; lp.WDZ = WDZ; lp.WD2 = WD2; lp.XBF = XBF;
  lp.HB = HB; lp.PT = PT; lp.ET = ET; lp.PHIX = PHIX; lp.ENCX = ENCX; lp.PHIZ = PHIZ;
  lp.DHP = DHP; lp.DECH = DECH;
  lp.H = H; lp.GH = GH; lp.GIX = GIX; lp.KLD = KLD; lp.RPART = RPART; lp.out = out;
  lp.eps = eps; lp.x = x;
  lp.prior_b = prior_b; lp.gru_bh = gru_bh; lp.gru_bi = gru_bi;
  lp.pm_b = prior_mean_b; lp.ps_b = prior_std_b; lp.em_b = enc_mean_b; lp.es_b = enc_std_b;
  lp.pz_b = phi_z_b; lp.phx_b = phi_x_b; lp.enc_b = enc_b; lp.dec1_b = dec1_b;
  lp.dec2_b = dec2_b;

  static int attr_done = 0;
  hipFuncSetAttribute(reinterpret_cast<const void*>(vrnn_loop),
                      hipFuncAttributeMaxDynamicSharedMemorySize, DYN_LDS);
  (void)attr_done;
  void* args[] = {&lp};
  hipLaunchCooperativeKernel(reinterpret_cast<const void*>(vrnn_loop), dim3(256), dim3(512),
                             args, DYN_LDS, stream);

  // epilogue: dec1_255 (slot 1), dec2_255, losses
  Epi e4{DECH, nullptr, dec1_b, DHP + (size_t)1 * BH, 1, HD};
  gemm_bt<2, 2><<<32, 256, 0, stream>>>(PHIZ + (size_t)1 * BH, HD, WDZ, HD, BATCH, HD, HD, e4);
  dec2_last<<<16, 256, 0, stream>>>(DECH, WD2, x, dec2_b, out, RPART);
  finalize_k<<<1, 256, 0, stream>>>(RPART, KLD, out);
}

// Round 4
// 27289.386 us; speedup vs baseline: 1.6743x; 1.3606x over previous
//
#include <hip/hip_runtime.h>
#include <algorithm>

typedef __bf16 bf16;
typedef __bf16 bf16x8 __attribute__((ext_vector_type(8)));
typedef float f32x4 __attribute__((ext_vector_type(4)));

// SEQ=256, B=128, XD=128, HD=1024, ZD=64
#define SEQ 256
#define BATCH 128
#define XD 128
#define HD 1024
#define ZD 64
#define MROWS (SEQ * BATCH)
#define BH (BATCH * HD)   // 131072
#define B3 (BATCH * 3072) // 393216
#define DYN_LDS 149824
#define NBLK 256

__device__ __forceinline__ f32x4 mfma16(bf16x8 a, bf16x8 b, f32x4 c) {
  return __builtin_amdgcn_mfma_f32_16x16x32_bf16(a, b, c, 0, 0, 0);
}
__device__ __forceinline__ float sigmoidf_(float x) { return 1.f / (1.f + __expf(-x)); }

// ---- fast grid barrier: monotonic counter, agent-scope release/acquire -------------
__device__ __forceinline__ void gbar(unsigned* cnt, int serial) {
  __syncthreads(); // all block threads done with phase (drains vmcnt per-wave)
  if (threadIdx.x == 0) {
    __hip_atomic_fetch_add(cnt, 1u, __ATOMIC_RELEASE, __HIP_MEMORY_SCOPE_AGENT);
    const unsigned tgt = (unsigned)serial * (unsigned)NBLK;
    while (__hip_atomic_load(cnt, __ATOMIC_RELAXED, __HIP_MEMORY_SCOPE_AGENT) < tgt)
      __builtin_amdgcn_s_sleep(1);
    __builtin_amdgcn_fence(__ATOMIC_ACQUIRE, "agent");
  }
  __syncthreads();
}

// ---------- generic mma (global A, global B) for prologue/tail kernels --------------
template <int MT, int NT>
__device__ __forceinline__ void mma_block(const bf16* __restrict__ a0, size_t aStride,
                                          const bf16* __restrict__ b0, size_t bStride,
                                          int K, f32x4 acc[MT][NT]) {
#pragma unroll 2
  for (int k = 0; k < K; k += 32) {
    bf16x8 af[MT], bfr[NT];
#pragma unroll
    for (int i = 0; i < MT; ++i) af[i] = *(const bf16x8*)(a0 + (size_t)i * aStride + k);
#pragma unroll
    for (int j = 0; j < NT; ++j) bfr[j] = *(const bf16x8*)(b0 + (size_t)j * bStride + k);
#pragma unroll
    for (int i = 0; i < MT; ++i)
#pragma unroll
      for (int j = 0; j < NT; ++j) acc[i][j] = mfma16(af[i], bfr[j], acc[i][j]);
  }
}

// ---------------- fp32 -> bf16 conversion (column slicing for concat splits) --------
__global__ void cvt_k(bf16* __restrict__ dst, const float* __restrict__ src, long n,
                      int cols, int src_ld, int col_off) {
  long i = (long)blockIdx.x * blockDim.x + threadIdx.x;
  long stride = (long)gridDim.x * blockDim.x;
  for (; i < n; i += stride) {
    long row = i / cols;
    int c = (int)(i - row * cols);
    dst[i] = (bf16)src[row * (long)src_ld + col_off + c];
  }
}

// ---------------- generic GEMM (B^T) for prologue ----------------------------------
struct Epi {
  bf16* C;
  float* Cf;
  const float* bias;
  const bf16* add;
  int relu;
  int ldc;
};

template <int MT, int NT>
__global__ void gemm_bt(const bf16* __restrict__ A, int lda, const bf16* __restrict__ B,
                        int ldb, int M, int N, int K, Epi e) {
  const int lane = threadIdx.x & 63;
  const int r = lane & 15, kb = lane >> 4;
  const int gw = blockIdx.x * (blockDim.x >> 6) + (threadIdx.x >> 6);
  const int nw = gridDim.x * (blockDim.x >> 6);
  const int ntm = M / (16 * MT), ntn = N / (16 * NT);
  for (int task = gw; task < ntm * ntn; task += nw) {
    int mt = task % ntm, nt = task / ntm;
    int m0 = mt * 16 * MT, n0 = nt * 16 * NT;
    f32x4 acc[MT][NT] = {};
    const bf16* a0 = A + (size_t)(m0 + r) * lda + kb * 8;
    const bf16* b0 = B + (size_t)(n0 + r) * ldb + kb * 8;
    mma_block<MT, NT>(a0, (size_t)16 * lda, b0, (size_t)16 * ldb, K, acc);
#pragma unroll
    for (int i = 0; i < MT; ++i)
#pragma unroll
      for (int j = 0; j < NT; ++j)
#pragma unroll
        for (int q = 0; q < 4; ++q) {
          size_t gm = (size_t)m0 + i * 16 + kb * 4 + q;
          int gn = n0 + j * 16 + r;
          float v = acc[i][j][q] + e.bias[gn];
          if (e.add) v += (float)e.add[gm * e.ldc + gn];
          if (e.relu) v = fmaxf(v, 0.f);
          if (e.Cf) e.Cf[gm * e.ldc + gn] = v;
          else e.C[gm * e.ldc + gn] = (bf16)v;
        }
  }
}

// ===================== the LDS-weight-pinned recurrence ==============================
struct LoopP {
  const bf16 *WA, *WB, *WPZ, *WIZ, *WIX, *WXX, *WPX, *WDZ, *WD2, *XBF;
  bf16 *HB, *PT, *ET, *PHIX, *ENCX, *PHIZ, *DHP, *DECH;
  float *H, *GH, *GIX, *KLD, *RPART, *out;
  unsigned* BAR;
  const float *eps, *x;
  const float *prior_b, *gru_bh, *gru_bi, *pm_b, *ps_b, *em_b, *es_b, *pz_b, *phx_b,
      *enc_b, *dec1_b, *dec2_b;
};

// stage 16 rows x K=1024 into k-major LDS unit: [128 kg][16 row][16B]
__device__ __forceinline__ void stage1024(char* lds, int off, const bf16* src) {
  for (int c = threadIdx.x; c < 2048; c += 512) {
    int kg = c & 127, rr = c >> 7;
    *(float4*)(lds + off + (((kg << 4) + rr) << 4)) =
        *(const float4*)(src + (size_t)rr * 1024 + kg * 8);
  }
}

template <int KK>
__device__ __forceinline__ void load_af(bf16x8* af, const bf16* A, int row, int lda, int k0,
                                        int kb) {
#pragma unroll
  for (int kk = 0; kk < KK; ++kk)
    af[kk] = *(const bf16x8*)(A + (size_t)row * lda + k0 + kk * 32 + kb * 8);
}

__device__ __forceinline__ f32x4 unit_mma32(const bf16x8* af, const char* slab, int kb, int r) {
  f32x4 acc = {};
#pragma unroll
  for (int kk = 0; kk < 32; ++kk)
    acc = mfma16(af[kk], *(const bf16x8*)(slab + ((((kk * 4 + kb) << 4) + r) << 4)), acc);
  return acc;
}

__global__ void __launch_bounds__(512, 2) vrnn_loop(LoopP p) {
  extern __shared__ char lds[];
  const int tid = threadIdx.x, lane = tid & 63, wv = tid >> 6;
  const int r = lane & 15, kb = lane >> 4;
  const int b = blockIdx.x;
  const bool special = b < 8;
  const int q = b - 8;
  int bs = 0; // barrier serial

  // ----- static unit assignment -----
  int p1n = 0, p1uid0 = 0;
  bool p1wdz = false;
  int p2n = 0, p2kind = -1, p2id0 = 0; // 0 dhp, 1 wxx, 2 wixa, 3 wd2
  int p3kind = 0, p3id = 0;            // 1 fused giz, 2 wixb
  int wpxn = 0, wpxid0 = 0;
  if (!special) {
    if (q < 64) {
      p1n = 1; p1uid0 = q; p3kind = 1; p3id = q;
    } else if (q < 96) {
      p1n = 2; p1uid0 = 384 + 2 * (q - 64); p1wdz = true;
      p2n = 1; p2kind = 2; p2id0 = q - 64;
    } else if (q < 224) {
      p1n = 2; p1uid0 = 64 + 2 * (q - 96);
      if (q < 128) { p2n = 2; p2kind = 0; p2id0 = 2 * (q - 96); }
      else if (q < 144) { p2n = 2; p2kind = 1; p2id0 = 2 * (q - 128); }
      else if (q < 176) { p2n = 1; p2kind = 1; p2id0 = 32 + (q - 144); }
      else { p2n = 1; p2kind = 2; p2id0 = 32 + (q - 176); }
      if (q >= 144) { p3kind = 2; p3id = q - 144; }
    } else if (q < 240) {
      p2n = 1; p2kind = 2; p2id0 = 32 + (q - 176);
      p3kind = 2; p3id = q - 144;
    } else {
      p2n = 1; p2kind = 3; p2id0 = q - 240;
      wpxn = 8; wpxid0 = 8 * (q - 240);
    }
  }
  const int p1off = 0;
  const int p2off = (q >= 224) ? 0 : 65536;
  const int p3off = (q < 64 || q >= 224) ? 32768 : 98304;
  const int scoff = 131072;
  const int wpxoff = 32768;

  // ----- one-time staging of weights into LDS -----
  if (special) {
    for (int c = tid; c < 8192; c += 512) {
      int kg = c & 7, rr = (c >> 3) & 15, u = c >> 7;
      *(float4*)(lds + u * 2048 + (((kg << 4) + rr) << 4)) =
          *(const float4*)(p.WPZ + (size_t)(u * 16 + rr) * 64 + kg * 8);
    }
  } else {
    for (int u = 0; u < p1n; ++u) {
      int uid = p1uid0 + u;
      const bf16* src = (uid < 384) ? p.WA + (size_t)uid * 16 * 1024
                                    : p.WDZ + (size_t)(uid - 384) * 16 * 1024;
      stage1024(lds, p1off + u * 32768, src);
    }
    for (int u = 0; u < p2n; ++u) {
      int id = p2id0 + u;
      const bf16* src = (p2kind == 0) ? p.WA + (size_t)(5120 + id * 16) * 1024
                      : (p2kind == 1) ? p.WXX + (size_t)id * 16 * 1024
                      : (p2kind == 2) ? p.WIX + (size_t)id * 16 * 1024
                                      : p.WD2 + (size_t)id * 16 * 1024;
      stage1024(lds, p2off + u * 32768, src);
    }
    if (p3kind == 1)
      for (int g = 0; g < 3; ++g)
        stage1024(lds, p3off + g * 32768, p.WIZ + (size_t)(g * 1024 + p3id * 16) * 1024);
    if (p3kind == 2) stage1024(lds, p3off, p.WIX + (size_t)(1536 + p3id * 16) * 1024);
    for (int u = 0; u < wpxn; ++u)
      if (tid < 256) {
        int kg = tid & 15, rr = tid >> 4;
        *(float4*)(lds + wpxoff + u * 4096 + (((kg << 4) + rr) << 4)) =
            *(const float4*)(p.WPX + (size_t)((wpxid0 + u) * 16 + rr) * 128 + kg * 8);
      }
  }
  __syncthreads();

  for (int t = 0; t < SEQ; ++t) {
    const int cur = t & 1, oth = cur ^ 1;

    // ================= Phase 1: prior|ench|gh (A=h), dec1 (A=phiz_{t-1}), phix_{t+1}
    if (!special) {
      if (p1n && (!p1wdz || t > 0)) {
        const bf16* A = p1wdz ? p.PHIZ + (size_t)oth * BH : p.HB;
        bf16x8 af[32];
        load_af<32>(af, A, wv * 16 + r, 1024, 0, kb);
        for (int u = 0; u < p1n; ++u) {
          f32x4 acc = unit_mma32(af, lds + p1off + u * 32768, kb, r);
          int uid = p1uid0 + u;
          int gn = uid * 16 + r;
#pragma unroll
          for (int qq = 0; qq < 4; ++qq) {
            int gm = wv * 16 + kb * 4 + qq;
            float v = acc[qq];
            if (uid < 64) {
              p.PT[gm * HD + gn] = (bf16)fmaxf(v + p.prior_b[gn], 0.f);
            } else if (uid < 128) {
              int c = gn - 1024;
              p.ET[gm * HD + c] =
                  (bf16)fmaxf(v + (float)p.ENCX[(size_t)cur * BH + gm * HD + c], 0.f);
            } else if (uid < 320) {
              int c = gn - 2048;
              p.GH[gm * 3072 + c] = v + p.gru_bh[c];
            } else { // wdz (dec1 for t-1)
              int c = (uid - 384) * 16 + r;
              float vv = v + (float)p.DHP[(size_t)oth * BH + gm * HD + c] + p.dec1_b[c];
              p.DECH[gm * HD + c] = (bf16)fmaxf(vv, 0.f);
            }
          }
        }
      }
      if (wpxn && t < SEQ - 1) { // phi_x_{t+1}, K=128
        bf16x8 af2[4];
        load_af<4>(af2, p.XBF + (size_t)(t + 1) * BATCH * XD, wv * 16 + r, 128, 0, kb);
        for (int u = 0; u < 8; ++u) {
          f32x4 acc = {};
#pragma unroll
          for (int kk = 0; kk < 4; ++kk)
            acc = mfma16(af2[kk],
                         *(const bf16x8*)(lds + wpxoff + u * 4096 +
                                          ((((kk * 4 + kb) << 4) + r) << 4)),
                         acc);
          int gn = (wpxid0 + u) * 16 + r;
#pragma unroll
          for (int qq = 0; qq < 4; ++qq) {
            int gm = wv * 16 + kb * 4 + qq;
            p.PHIX[gm * HD + gn] = (bf16)fmaxf(acc[qq] + p.phx_b[gn], 0.f);
          }
        }
      }
    }
    gbar(p.BAR, ++bs);

    // ================= Phase 2: special meanstd/z/kld/phiz; dhp/wxx/wixa/wd2
    if (special) {
      const int s = b, m0 = s * 16;
      const int mat = wv & 3, half = wv >> 2;
      float* sm = (float*)(lds + 131072); // [4][16][64]
      bf16* zs = (bf16*)(lds + 147456);   // [16][72]
      float* red = (float*)(lds + 149760);
      {
        const bf16* A = (mat < 2) ? p.PT : p.ET;
        bf16x8 af[32];
        load_af<32>(af, A, m0 + r, 1024, 0, kb);
        const float* bw = mat == 0 ? p.pm_b : mat == 1 ? p.ps_b : mat == 2 ? p.em_b : p.es_b;
#pragma unroll 1
        for (int nt = 0; nt < 2; ++nt) {
          int colb = half * 32 + nt * 16;
          f32x4 acc = {};
#pragma unroll
          for (int kk = 0; kk < 32; ++kk)
            acc = mfma16(af[kk],
                         *(const bf16x8*)(p.WB + (size_t)(mat * 64 + colb + r) * 1024 +
                                          kk * 32 + kb * 8),
                         acc);
#pragma unroll
          for (int qq = 0; qq < 4; ++qq)
            sm[mat * 1024 + (kb * 4 + qq) * 64 + colb + r] = acc[qq] + bw[colb + r];
        }
      }
      __syncthreads();
      float kacc = 0.f;
      for (int e = tid; e < 1024; e += 512) {
        int row = e >> 6, col = e & 63;
        float pm = sm[row * 64 + col], ps = sm[1024 + row * 64 + col];
        float em = sm[2048 + row * 64 + col], es = sm[3072 + row * 64 + col];
        float ev = p.eps[((size_t)t * BATCH + m0 + row) * ZD + col];
        zs[row * 72 + col] = (bf16)(em + ev * __expf(0.5f * es));
        float dm = em - pm;
        kacc += 1.f + es - dm * dm - __expf(es - ps);
      }
#pragma unroll
      for (int off = 32; off; off >>= 1) kacc += __shfl_down(kacc, off, 64);
      if (lane == 0) red[wv] = kacc;
      __syncthreads();
      if (tid == 0) {
        float ss = 0.f;
        for (int i = 0; i < 8; ++i) ss += red[i];
        p.KLD[t * 8 + s] = ss;
      }
      // phiz: A = zs (LDS), B = WPZ (LDS), N=1024 over 8 waves
      bf16x8 afz[2];
      afz[0] = *(const bf16x8*)(zs + r * 72 + kb * 8);
      afz[1] = *(const bf16x8*)(zs + r * 72 + 32 + kb * 8);
#pragma unroll 1
      for (int j = 0; j < 8; ++j) {
        int u = wv * 8 + j;
        f32x4 acc = {};
#pragma unroll
        for (int kk = 0; kk < 2; ++kk)
          acc = mfma16(afz[kk],
                       *(const bf16x8*)(lds + u * 2048 + ((((kk * 4 + kb) << 4) + r) << 4)),
                       acc);
        int gn = u * 16 + r;
#pragma unroll
        for (int qq = 0; qq < 4; ++qq) {
          int gm = m0 + kb * 4 + qq;
          p.PHIZ[(size_t)cur * BH + gm * HD + gn] = (bf16)fmaxf(acc[qq] + p.pz_b[gn], 0.f);
        }
      }
    } else if (p2n) {
      bool go = (p2kind == 0) || (p2kind == 3 ? (t > 0) : (t < SEQ - 1));
      if (go) {
        const bf16* A = (p2kind == 0) ? p.HB : (p2kind == 3) ? p.DECH : p.PHIX;
        bf16x8 af[32];
        load_af<32>(af, A, wv * 16 + r, 1024, 0, kb);
        float racc = 0.f;
        for (int u = 0; u < p2n; ++u) {
          f32x4 acc = unit_mma32(af, lds + p2off + u * 32768, kb, r);
          int id = p2id0 + u;
          int c = id * 16 + r;
#pragma unroll
          for (int qq = 0; qq < 4; ++qq) {
            int gm = wv * 16 + kb * 4 + qq;
            if (p2kind == 0) {
              p.DHP[(size_t)cur * BH + gm * HD + c] = (bf16)acc[qq];
            } else if (p2kind == 1) {
              p.ENCX[(size_t)oth * BH + gm * HD + c] = (bf16)(acc[qq] + p.enc_b[c]);
            } else if (p2kind == 2) {
              p.GIX[(size_t)oth * B3 + gm * 3072 + c] = acc[qq] + p.gru_bi[c];
            } else { // wd2: dec2 for t-1 + recon + sigmoid out
              float l = acc[qq] + p.dec2_b[c];
              size_t oi = ((size_t)(t - 1) * BATCH + gm) * XD + c;
              p.out[2 + oi] = sigmoidf_(l);
              float spp = fmaxf(l, 0.f) + log1pf(__expf(-fabsf(l)));
              racc += spp - p.x[oi] * l;
            }
          }
        }
        if (p2kind == 3) {
#pragma unroll
          for (int off = 32; off; off >>= 1) racc += __shfl_down(racc, off, 64);
          if (lane == 0) p.RPART[(t - 1) * 64 + p2id0 * 8 + wv] = racc;
        }
      }
    }
    gbar(p.BAR, ++bs);

    // ================= Phase 3: fused giz+GRU (K-split), wixb
    if (!special) {
      if (p3kind == 1) {
        const int khalf = wv >> 2;
        float* sc = (float*)(lds + scoff); // [4][3][256]
#pragma unroll 1
        for (int pass = 0; pass < 2; ++pass) {
          int mt = (wv & 3) + 4 * pass;
          bf16x8 af[16];
          load_af<16>(af, p.PHIZ + (size_t)cur * BH, mt * 16 + r, 1024, khalf * 512, kb);
          f32x4 a3[3] = {};
#pragma unroll
          for (int kk = 0; kk < 16; ++kk) {
            bf16x8 a = af[kk];
#pragma unroll
            for (int g = 0; g < 3; ++g)
              a3[g] = mfma16(a,
                             *(const bf16x8*)(lds + p3off + g * 32768 +
                                              (((((khalf * 16 + kk) * 4 + kb) << 4) + r) << 4)),
                             a3[g]);
          }
          if (khalf) {
#pragma unroll
            for (int g = 0; g < 3; ++g)
#pragma unroll
              for (int qq = 0; qq < 4; ++qq)
                sc[((wv & 3) * 3 + g) * 256 + (kb * 4 + qq) * 16 + r] = a3[g][qq];
          }
          __syncthreads();
          if (!khalf) {
            int c = p3id * 16 + r;
#pragma unroll
            for (int qq = 0; qq < 4; ++qq) {
              int gm = mt * 16 + kb * 4 + qq;
              int si = (kb * 4 + qq) * 16 + r;
              float ir = a3[0][qq] + sc[((wv & 3) * 3 + 0) * 256 + si] +
                         p.GIX[(size_t)cur * B3 + gm * 3072 + c];
              float iz = a3[1][qq] + sc[((wv & 3) * 3 + 1) * 256 + si] +
                         p.GIX[(size_t)cur * B3 + gm * 3072 + c + 1024];
              float in_ = a3[2][qq] + sc[((wv & 3) * 3 + 2) * 256 + si] +
                          p.GIX[(size_t)cur * B3 + gm * 3072 + c + 2048];
              float hr = p.GH[gm * 3072 + c], hz = p.GH[gm * 3072 + c + 1024],
                    hn = p.GH[gm * 3072 + c + 2048];
              float rr2 = sigmoidf_(ir + hr), zg = sigmoidf_(iz + hz);
              float nn = tanhf(in_ + rr2 * hn);
              float hv = p.H[gm * HD + c];
              float hnew = (1.f - zg) * nn + zg * hv;
              p.H[gm * HD + c] = hnew;
              p.HB[gm * HD + c] = (bf16)hnew;
            }
          }
          __syncthreads();
        }
      } else if (p3kind == 2 && t < SEQ - 1) {
        bf16x8 af[32];
        load_af<32>(af, p.PHIX, wv * 16 + r, 1024, 0, kb);
        f32x4 acc = unit_mma32(af, lds + p3off, kb, r);
        int c = 1536 + p3id * 16 + r;
#pragma unroll
        for (int qq = 0; qq < 4; ++qq) {
          int gm = wv * 16 + kb * 4 + qq;
          p.GIX[(size_t)oth * B3 + gm * 3072 + c] = acc[qq] + p.gru_bi[c];
        }
      }
    }
    gbar(p.BAR, ++bs);
  }
}

// ---------------- epilogue dec2 for t=255 -------------------------------------------
__global__ void dec2_last(const bf16* __restrict__ A, const bf16* __restrict__ W,
                          const float* __restrict__ x, const float* __restrict__ b2,
                          float* __restrict__ out, float* __restrict__ rpart) {
  const int lane = threadIdx.x & 63;
  const int r = lane & 15, kb = lane >> 4;
  const int w = blockIdx.x * 4 + (threadIdx.x >> 6); // 0..63
  const int m0 = (w & 7) * 16, n0 = (w >> 3) * 16;
  f32x4 acc[1][1] = {};
  const bf16* a0 = A + (size_t)(m0 + r) * HD + kb * 8;
  const bf16* b0 = W + (size_t)(n0 + r) * HD + kb * 8;
  mma_block<1, 1>(a0, 0, b0, (size_t)16 * HD, HD, acc);
  float racc = 0.f;
#pragma unroll
  for (int q = 0; q < 4; ++q) {
    int gm = m0 + kb * 4 + q, gn = n0 + r;
    float l = acc[0][0][q] + b2[gn];
    size_t oi = ((size_t)255 * BATCH + gm) * XD + gn;
    out[2 + oi] = sigmoidf_(l);
    float spp = fmaxf(l, 0.f) + log1pf(__expf(-fabsf(l)));
    racc += spp - x[oi] * l;
  }
#pragma unroll
  for (int off = 32; off; off >>= 1) racc += __shfl_down(racc, off, 64);
  if (lane == 0) rpart[255 * 64 + w] = racc;
}

__global__ void finalize_k(const float* __restrict__ rp, const float* __restrict__ kp,
                           float* __restrict__ out) {
  __shared__ float s[256];
  int tid = threadIdx.x;
  float a = 0.f;
  for (int i = tid; i < 256 * 64; i += 256) a += rp[i];
  s[tid] = a;
  __syncthreads();
  for (int off = 128; off > 0; off >>= 1) {
    if (tid < off) s[tid] += s[tid + off];
    __syncthreads();
  }
  if (tid == 0) out[0] = s[0] / (float)BATCH;
  __syncthreads();
  float bb = 0.f;
  for (int i = tid; i < 2048; i += 256) bb += kp[i];
  s[tid] = bb;
  __syncthreads();
  for (int off = 128; off > 0; off >>= 1) {
    if (tid < off) s[tid] += s[tid + off];
    __syncthreads();
  }
  if (tid == 0) out[1] = -0.5f * s[0] / (float)BATCH;
}

__global__ void sentinel_k(float* out) {
  if (threadIdx.x == 0) { out[0] = 1e9f; out[1] = 1e9f; }
}

// =====================================================================================
extern "C" void kernel_launch(void* const* d_in, const int* in_sizes, int n_in, void* d_out,
                              int out_size, void* d_ws, size_t ws_size, hipStream_t stream) {
  const float* x = (const float*)d_in[0];
  const float* eps = (const float*)d_in[1];
  const float* phi_x_W = (const float*)d_in[2];
  const float* phi_x_b = (const float*)d_in[3];
  const float* enc_W = (const float*)d_in[4];
  const float* enc_b = (const float*)d_in[5];
  const float* enc_mean_W = (const float*)d_in[6];
  const float* enc_mean_b = (const float*)d_in[7];
  const float* enc_std_W = (const float*)d_in[8];
  const float* enc_std_b = (const float*)d_in[9];
  const float* prior_W = (const float*)d_in[10];
  const float* prior_b = (const float*)d_in[11];
  const float* prior_mean_W = (const float*)d_in[12];
  const float* prior_mean_b = (const float*)d_in[13];
  const float* prior_std_W = (const float*)d_in[14];
  const float* prior_std_b = (const float*)d_in[15];
  const float* phi_z_W = (const float*)d_in[16];
  const float* phi_z_b = (const float*)d_in[17];
  const float* dec1_W = (const float*)d_in[18];
  const float* dec1_b = (const float*)d_in[19];
  const float* dec2_W = (const float*)d_in[20];
  const float* dec2_b = (const float*)d_in[21];
  const float* gru_Wi = (const float*)d_in[22];
  const float* gru_Wh = (const float*)d_in[23];
  const float* gru_bi = (const float*)d_in[24];
  const float* gru_bh = (const float*)d_in[25];
  float* out = (float*)d_out;

  char* w = (char*)d_ws;
  auto carve = [&](size_t bytes) {
    char* pp = w;
    w += (bytes + 255) & ~(size_t)255;
    return pp;
  };
  bf16* WA = (bf16*)carve((size_t)6144 * HD * 2);  // [prior;ench;gh;dhp] row-major [.][1024]
  bf16* WB = (bf16*)carve((size_t)256 * HD * 2);   // [pm;ps;em;es]
  bf16* WPZ = (bf16*)carve((size_t)HD * ZD * 2);
  bf16* WIZ = (bf16*)carve((size_t)3072 * HD * 2); // gru_Wi[:,1024:]
  bf16* WIX = (bf16*)carve((size_t)3072 * HD * 2); // gru_Wi[:,:1024]
  bf16* WXX = (bf16*)carve((size_t)HD * HD * 2);   // enc_W[:,:1024]
  bf16* WPX = (bf16*)carve((size_t)HD * XD * 2);
  bf16* WDZ = (bf16*)carve((size_t)HD * HD * 2);   // dec1_W[:,:1024]
  bf16* WD2 = (bf16*)carve((size_t)XD * HD * 2);
  bf16* XBF = (bf16*)carve((size_t)MROWS * XD * 2);
  float* H = (float*)carve((size_t)BH * 4);
  bf16* HB = (bf16*)carve((size_t)BH * 2);
  bf16* PT = (bf16*)carve((size_t)BH * 2);
  bf16* ET = (bf16*)carve((size_t)BH * 2);
  float* GH = (float*)carve((size_t)B3 * 4);
  bf16* PHIX = (bf16*)carve((size_t)BH * 2);
  bf16* ENCX = (bf16*)carve((size_t)2 * BH * 2);
  bf16* PHIZ = (bf16*)carve((size_t)2 * BH * 2);
  bf16* DHP = (bf16*)carve((size_t)2 * BH * 2);
  bf16* DECH = (bf16*)carve((size_t)BH * 2);
  float* GIX = (float*)carve((size_t)2 * B3 * 4);
  float* KLD = (float*)carve((size_t)SEQ * 8 * 4);
  float* RPART = (float*)carve((size_t)SEQ * 64 * 4);
  unsigned* BAR = (unsigned*)carve(256);
  if ((size_t)(w - (char*)d_ws) > ws_size) {
    sentinel_k<<<1, 64, 0, stream>>>(out);
    return;
  }

  auto cvt = [&](bf16* dst, const float* src, long n, int cols, int ld, int off) {
    int grid = (int)std::min((n + 255) / 256, (long)2048);
    cvt_k<<<grid, 256, 0, stream>>>(dst, src, n, cols, ld, off);
  };
  cvt(WA, prior_W, (long)HD * HD, HD, HD, 0);
  cvt(WA + (size_t)HD * HD, enc_W, (long)HD * HD, HD, 2 * HD, HD);
  cvt(WA + (size_t)2048 * HD, gru_Wh, (long)3072 * HD, HD, HD, 0);
  cvt(WA + (size_t)5120 * HD, dec1_W, (long)HD * HD, HD, 2 * HD, HD);
  cvt(WB, prior_mean_W, (long)ZD * HD, HD, HD, 0);
  cvt(WB + (size_t)64 * HD, prior_std_W, (long)ZD * HD, HD, HD, 0);
  cvt(WB + (size_t)128 * HD, enc_mean_W, (long)ZD * HD, HD, HD, 0);
  cvt(WB + (size_t)192 * HD, enc_std_W, (long)ZD * HD, HD, HD, 0);
  cvt(WPZ, phi_z_W, (long)HD * ZD, ZD, ZD, 0);
  cvt(WIZ, gru_Wi, (long)3072 * HD, HD, 2 * HD, HD);
  cvt(WIX, gru_Wi, (long)3072 * HD, HD, 2 * HD, 0);
  cvt(WXX, enc_W, (long)HD * HD, HD, 2 * HD, 0);
  cvt(WPX, phi_x_W, (long)HD * XD, XD, XD, 0);
  cvt(WDZ, dec1_W, (long)HD * HD, HD, 2 * HD, 0);
  cvt(WD2, dec2_W, (long)XD * HD, HD, HD, 0);
  cvt(XBF, x, (long)MROWS * XD, XD, XD, 0);

  hipMemsetAsync(H, 0, (size_t)BH * 4, stream);
  hipMemsetAsync(HB, 0, (size_t)BH * 2, stream);
  hipMemsetAsync(BAR, 0, 256, stream);

  // prologue: phi_x_0 -> encx_0, gix_0 (slot 0)
  Epi e1{PHIX, nullptr, phi_x_b, nullptr, 1, HD};
  gemm_bt<2, 2><<<32, 256, 0, stream>>>(XBF, XD, WPX, XD, BATCH, HD, XD, e1);
  Epi e2{ENCX, nullptr, enc_b, nullptr, 0, HD};
  gemm_bt<2, 2><<<32, 256, 0, stream>>>(PHIX, HD, WXX, HD, BATCH, HD, HD, e2);
  Epi e3{nullptr, GIX, gru_bi, nullptr, 0, 3072};
  gemm_bt<2, 2><<<96, 256, 0, stream>>>(PHIX, HD, WIX, HD, BATCH, 3072, HD, e3);

  LoopP lp;
  lp.WA = WA; lp.WB = WB; lp.WPZ = WPZ; lp.WIZ = WIZ; lp.WIX = WIX; lp.WXX = WXX;
  lp.WPX = WPX; lp.WDZ = WDZ; lp.WD2 = WD2; lp.XBF = XBF;
  lp.HB = HB; lp.PT = PT; lp.ET = ET; lp.PHIX = PHIX; lp.ENCX = ENCX; lp.PHIZ = PHIZ;
  lp.DHP = DHP; lp.DECH = DECH;
  lp.H = H; lp.GH = GH; lp.GIX = GIX; lp.KLD = KLD; lp.RPART = RPART; lp.out = out;
  lp.BAR = BAR;
  lp.eps = eps; lp.x = x;
  lp.prior_b = prior_b; lp.gru_bh = gru_bh; lp.gru_bi = gru_bi;
  lp.pm_b = prior_mean_b; lp.ps_b = prior_std_b; lp.em_b = enc_mean_b; lp.es_b = enc_std_b;
  lp.pz_b = phi_z_b; lp.phx_b = phi_x_b; lp.enc_b = enc_b; lp.dec1_b = dec1_b;
  lp.dec2_b = dec2_b;

  hipFuncSetAttribute(reinterpret_cast<const void*>(vrnn_loop),
                      hipFuncAttributeMaxDynamicSharedMemorySize, DYN_LDS);
  void* args[] = {&lp};
  hipLaunchCooperativeKernel(reinterpret_cast<const void*>(vrnn_loop), dim3(NBLK), dim3(512),
                             args, DYN_LDS, stream);

  // epilogue: dec1_255 (slot 1), dec2_255, losses
  Epi e4{DECH, nullptr, dec1_b, DHP + (size_t)1 * BH, 1, HD};
  gemm_bt<2, 2><<<32, 256, 0, stream>>>(PHIZ + (size_t)1 * BH, HD, WDZ, HD, BATCH, HD, HD, e4);
  dec2_last<<<16, 256, 0, stream>>>(DECH, WD2, x, dec2_b, out, RPART);
  finalize_k<<<1, 256, 0, stream>>>(RPART, KLD, out);
}

// Round 5
// 25784.799 us; speedup vs baseline: 1.7720x; 1.0584x over previous
//
#include <hip/hip_runtime.h>
#include <algorithm>

typedef __bf16 bf16;
typedef __bf16 bf16x8 __attribute__((ext_vector_type(8)));
typedef float f32x4 __attribute__((ext_vector_type(4)));

// SEQ=256, B=128, XD=128, HD=1024, ZD=64
#define SEQ 256
#define BATCH 128
#define XD 128
#define HD 1024
#define ZD 64
#define MROWS (SEQ * BATCH)
#define BH (BATCH * HD)   // 131072
#define B3 (BATCH * 3072) // 393216
#define DYN_LDS 149824
#define NBLK 256

__device__ __forceinline__ f32x4 mfma16(bf16x8 a, bf16x8 b, f32x4 c) {
  return __builtin_amdgcn_mfma_f32_16x16x32_bf16(a, b, c, 0, 0, 0);
}
__device__ __forceinline__ float sigmoidf_(float x) { return 1.f / (1.f + __expf(-x)); }

// ---- distributed flag-array grid barrier (no RMW contention) -----------------------
// flags[i*32]: monotonic serial of block i (128B spacing). Arrival = one release
// store to own flag; wait = threads 0..NBLK-1 poll one flag each (parallel reads).
__device__ __forceinline__ void gbar(unsigned* flags, unsigned serial) {
  __syncthreads(); // drains this block's outstanding ops (compiler emits waitcnt)
  if (threadIdx.x == 0)
    __hip_atomic_store(flags + (size_t)blockIdx.x * 32, serial, __ATOMIC_RELEASE,
                       __HIP_MEMORY_SCOPE_AGENT);
  if (threadIdx.x < NBLK) {
    while (__hip_atomic_load(flags + (size_t)threadIdx.x * 32, __ATOMIC_RELAXED,
                             __HIP_MEMORY_SCOPE_AGENT) < serial)
      __builtin_amdgcn_s_sleep(1);
    __builtin_amdgcn_fence(__ATOMIC_ACQUIRE, "agent");
  }
  __syncthreads();
}

// ---------- generic mma (global A, global B) for prologue/tail kernels --------------
template <int MT, int NT>
__device__ __forceinline__ void mma_block(const bf16* __restrict__ a0, size_t aStride,
                                          const bf16* __restrict__ b0, size_t bStride,
                                          int K, f32x4 acc[MT][NT]) {
#pragma unroll 2
  for (int k = 0; k < K; k += 32) {
    bf16x8 af[MT], bfr[NT];
#pragma unroll
    for (int i = 0; i < MT; ++i) af[i] = *(const bf16x8*)(a0 + (size_t)i * aStride + k);
#pragma unroll
    for (int j = 0; j < NT; ++j) bfr[j] = *(const bf16x8*)(b0 + (size_t)j * bStride + k);
#pragma unroll
    for (int i = 0; i < MT; ++i)
#pragma unroll
      for (int j = 0; j < NT; ++j) acc[i][j] = mfma16(af[i], bfr[j], acc[i][j]);
  }
}

// ---------------- fp32 -> bf16 conversion (column slicing for concat splits) --------
__global__ void cvt_k(bf16* __restrict__ dst, const float* __restrict__ src, long n,
                      int cols, int src_ld, int col_off) {
  long i = (long)blockIdx.x * blockDim.x + threadIdx.x;
  long stride = (long)gridDim.x * blockDim.x;
  for (; i < n; i += stride) {
    long row = i / cols;
    int c = (int)(i - row * cols);
    dst[i] = (bf16)src[row * (long)src_ld + col_off + c];
  }
}

// ---------------- generic GEMM (B^T) for prologue ----------------------------------
struct Epi {
  bf16* C;
  float* Cf;
  const float* bias;
  const bf16* add;
  int relu;
  int ldc;
};

template <int MT, int NT>
__global__ void gemm_bt(const bf16* __restrict__ A, int lda, const bf16* __restrict__ B,
                        int ldb, int M, int N, int K, Epi e) {
  const int lane = threadIdx.x & 63;
  const int r = lane & 15, kb = lane >> 4;
  const int gw = blockIdx.x * (blockDim.x >> 6) + (threadIdx.x >> 6);
  const int nw = gridDim.x * (blockDim.x >> 6);
  const int ntm = M / (16 * MT), ntn = N / (16 * NT);
  for (int task = gw; task < ntm * ntn; task += nw) {
    int mt = task % ntm, nt = task / ntm;
    int m0 = mt * 16 * MT, n0 = nt * 16 * NT;
    f32x4 acc[MT][NT] = {};
    const bf16* a0 = A + (size_t)(m0 + r) * lda + kb * 8;
    const bf16* b0 = B + (size_t)(n0 + r) * ldb + kb * 8;
    mma_block<MT, NT>(a0, (size_t)16 * lda, b0, (size_t)16 * ldb, K, acc);
#pragma unroll
    for (int i = 0; i < MT; ++i)
#pragma unroll
      for (int j = 0; j < NT; ++j)
#pragma unroll
        for (int q = 0; q < 4; ++q) {
          size_t gm = (size_t)m0 + i * 16 + kb * 4 + q;
          int gn = n0 + j * 16 + r;
          float v = acc[i][j][q] + e.bias[gn];
          if (e.add) v += (float)e.add[gm * e.ldc + gn];
          if (e.relu) v = fmaxf(v, 0.f);
          if (e.Cf) e.Cf[gm * e.ldc + gn] = v;
          else e.C[gm * e.ldc + gn] = (bf16)v;
        }
  }
}

// ===================== the LDS-weight-pinned recurrence ==============================
struct LoopP {
  const bf16 *WA, *WB, *WPZ, *WIZ, *WIX, *WXX, *WPX, *WDZ, *WD2, *XBF;
  bf16 *HB, *PT, *ET, *PHIX, *ENCX, *PHIZ, *DHP, *DECH;
  float *H, *GH, *GIX, *KLD, *RPART, *out;
  unsigned* BAR;
  const float *eps, *x;
  const float *prior_b, *gru_bh, *gru_bi, *pm_b, *ps_b, *em_b, *es_b, *pz_b, *phx_b,
      *enc_b, *dec1_b, *dec2_b;
};

// stage 16 rows x K=1024 into k-major LDS unit: [128 kg][16 row][16B]
__device__ __forceinline__ void stage1024(char* lds, int off, const bf16* src) {
  for (int c = threadIdx.x; c < 2048; c += 512) {
    int kg = c & 127, rr = c >> 7;
    *(float4*)(lds + off + (((kg << 4) + rr) << 4)) =
        *(const float4*)(src + (size_t)rr * 1024 + kg * 8);
  }
}

template <int KK>
__device__ __forceinline__ void load_af(bf16x8* af, const bf16* A, int row, int lda, int k0,
                                        int kb) {
#pragma unroll
  for (int kk = 0; kk < KK; ++kk)
    af[kk] = *(const bf16x8*)(A + (size_t)row * lda + k0 + kk * 32 + kb * 8);
}

__device__ __forceinline__ f32x4 unit_mma32(const bf16x8* af, const char* slab, int kb, int r) {
  f32x4 acc = {};
#pragma unroll
  for (int kk = 0; kk < 32; ++kk)
    acc = mfma16(af[kk], *(const bf16x8*)(slab + ((((kk * 4 + kb) << 4) + r) << 4)), acc);
  return acc;
}

__global__ void __launch_bounds__(512, 2) vrnn_loop(LoopP p) {
  extern __shared__ char lds[];
  const int tid = threadIdx.x, lane = tid & 63, wv = tid >> 6;
  const int r = lane & 15, kb = lane >> 4;
  const int b = blockIdx.x;
  const bool special = b < 8;
  const int q = b - 8;
  unsigned bs = 0; // barrier serial

  // ----- static unit assignment -----
  int p1n = 0, p1uid0 = 0;
  bool p1wdz = false;
  int p2n = 0, p2kind = -1, p2id0 = 0; // 0 dhp, 1 wxx, 2 wixa, 3 wd2
  int p3kind = 0, p3id = 0;            // 1 fused giz, 2 wixb
  int wpxn = 0, wpxid0 = 0;
  if (!special) {
    if (q < 64) {
      p1n = 1; p1uid0 = q; p3kind = 1; p3id = q;
    } else if (q < 96) {
      p1n = 2; p1uid0 = 384 + 2 * (q - 64); p1wdz = true;
      p2n = 1; p2kind = 2; p2id0 = q - 64;
    } else if (q < 224) {
      p1n = 2; p1uid0 = 64 + 2 * (q - 96);
      if (q < 128) { p2n = 2; p2kind = 0; p2id0 = 2 * (q - 96); }
      else if (q < 144) { p2n = 2; p2kind = 1; p2id0 = 2 * (q - 128); }
      else if (q < 176) { p2n = 1; p2kind = 1; p2id0 = 32 + (q - 144); }
      else { p2n = 1; p2kind = 2; p2id0 = 32 + (q - 176); }
      if (q >= 144) { p3kind = 2; p3id = q - 144; }
    } else if (q < 240) {
      p2n = 1; p2kind = 2; p2id0 = 32 + (q - 176);
      p3kind = 2; p3id = q - 144;
    } else {
      p2n = 1; p2kind = 3; p2id0 = q - 240;
      wpxn = 8; wpxid0 = 8 * (q - 240);
    }
  }
  const int p1off = 0;
  const int p2off = (q >= 224) ? 0 : 65536;
  const int p3off = (q < 64 || q >= 224) ? 32768 : 98304;
  const int scoff = 131072;
  const int wpxoff = 32768;

  // ----- one-time staging of weights into LDS -----
  if (special) {
    for (int c = tid; c < 8192; c += 512) {
      int kg = c & 7, rr = (c >> 3) & 15, u = c >> 7;
      *(float4*)(lds + u * 2048 + (((kg << 4) + rr) << 4)) =
          *(const float4*)(p.WPZ + (size_t)(u * 16 + rr) * 64 + kg * 8);
    }
  } else {
    for (int u = 0; u < p1n; ++u) {
      int uid = p1uid0 + u;
      const bf16* src = (uid < 384) ? p.WA + (size_t)uid * 16 * 1024
                                    : p.WDZ + (size_t)(uid - 384) * 16 * 1024;
      stage1024(lds, p1off + u * 32768, src);
    }
    for (int u = 0; u < p2n; ++u) {
      int id = p2id0 + u;
      const bf16* src = (p2kind == 0) ? p.WA + (size_t)(5120 + id * 16) * 1024
                      : (p2kind == 1) ? p.WXX + (size_t)id * 16 * 1024
                      : (p2kind == 2) ? p.WIX + (size_t)id * 16 * 1024
                                      : p.WD2 + (size_t)id * 16 * 1024;
      stage1024(lds, p2off + u * 32768, src);
    }
    if (p3kind == 1)
      for (int g = 0; g < 3; ++g)
        stage1024(lds, p3off + g * 32768, p.WIZ + (size_t)(g * 1024 + p3id * 16) * 1024);
    if (p3kind == 2) stage1024(lds, p3off, p.WIX + (size_t)(1536 + p3id * 16) * 1024);
    for (int u = 0; u < wpxn; ++u)
      if (tid < 256) {
        int kg = tid & 15, rr = tid >> 4;
        *(float4*)(lds + wpxoff + u * 4096 + (((kg << 4) + rr) << 4)) =
            *(const float4*)(p.WPX + (size_t)((wpxid0 + u) * 16 + rr) * 128 + kg * 8);
      }
  }
  __syncthreads();

  for (int t = 0; t < SEQ; ++t) {
    const int cur = t & 1, oth = cur ^ 1;

    // ================= Phase 1: prior|ench|gh (A=h), dec1 (A=phiz_{t-1}), phix_{t+1}
    if (!special) {
      if (p1n && (!p1wdz || t > 0)) {
        const bf16* A = p1wdz ? p.PHIZ + (size_t)oth * BH : p.HB;
        bf16x8 af[32];
        load_af<32>(af, A, wv * 16 + r, 1024, 0, kb);
        for (int u = 0; u < p1n; ++u) {
          f32x4 acc = unit_mma32(af, lds + p1off + u * 32768, kb, r);
          int uid = p1uid0 + u;
          int gn = uid * 16 + r;
#pragma unroll
          for (int qq = 0; qq < 4; ++qq) {
            int gm = wv * 16 + kb * 4 + qq;
            float v = acc[qq];
            if (uid < 64) {
              p.PT[gm * HD + gn] = (bf16)fmaxf(v + p.prior_b[gn], 0.f);
            } else if (uid < 128) {
              int c = gn - 1024;
              p.ET[gm * HD + c] =
                  (bf16)fmaxf(v + (float)p.ENCX[(size_t)cur * BH + gm * HD + c], 0.f);
            } else if (uid < 320) {
              int c = gn - 2048;
              p.GH[gm * 3072 + c] = v + p.gru_bh[c];
            } else { // wdz (dec1 for t-1)
              int c = (uid - 384) * 16 + r;
              float vv = v + (float)p.DHP[(size_t)oth * BH + gm * HD + c] + p.dec1_b[c];
              p.DECH[gm * HD + c] = (bf16)fmaxf(vv, 0.f);
            }
          }
        }
      }
      if (wpxn && t < SEQ - 1) { // phi_x_{t+1}, K=128
        bf16x8 af2[4];
        load_af<4>(af2, p.XBF + (size_t)(t + 1) * BATCH * XD, wv * 16 + r, 128, 0, kb);
        for (int u = 0; u < 8; ++u) {
          f32x4 acc = {};
#pragma unroll
          for (int kk = 0; kk < 4; ++kk)
            acc = mfma16(af2[kk],
                         *(const bf16x8*)(lds + wpxoff + u * 4096 +
                                          ((((kk * 4 + kb) << 4) + r) << 4)),
                         acc);
          int gn = (wpxid0 + u) * 16 + r;
#pragma unroll
          for (int qq = 0; qq < 4; ++qq) {
            int gm = wv * 16 + kb * 4 + qq;
            p.PHIX[gm * HD + gn] = (bf16)fmaxf(acc[qq] + p.phx_b[gn], 0.f);
          }
        }
      }
    }
    gbar(p.BAR, ++bs);

    // ================= Phase 2: special meanstd/z/kld/phiz; dhp/wxx/wixa/wd2
    if (special) {
      const int s = b, m0 = s * 16;
      const int mat = wv & 3, half = wv >> 2;
      float* sm = (float*)(lds + 131072); // [4][16][64]
      bf16* zs = (bf16*)(lds + 147456);   // [16][72]
      float* red = (float*)(lds + 149760);
      {
        const bf16* A = (mat < 2) ? p.PT : p.ET;
        bf16x8 af[32];
        load_af<32>(af, A, m0 + r, 1024, 0, kb);
        const float* bw = mat == 0 ? p.pm_b : mat == 1 ? p.ps_b : mat == 2 ? p.em_b : p.es_b;
#pragma unroll 1
        for (int nt = 0; nt < 2; ++nt) {
          int colb = half * 32 + nt * 16;
          f32x4 acc = {};
#pragma unroll
          for (int kk = 0; kk < 32; ++kk)
            acc = mfma16(af[kk],
                         *(const bf16x8*)(p.WB + (size_t)(mat * 64 + colb + r) * 1024 +
                                          kk * 32 + kb * 8),
                         acc);
#pragma unroll
          for (int qq = 0; qq < 4; ++qq)
            sm[mat * 1024 + (kb * 4 + qq) * 64 + colb + r] = acc[qq] + bw[colb + r];
        }
      }
      __syncthreads();
      float kacc = 0.f;
      for (int e = tid; e < 1024; e += 512) {
        int row = e >> 6, col = e & 63;
        float pm = sm[row * 64 + col], ps = sm[1024 + row * 64 + col];
        float em = sm[2048 + row * 64 + col], es = sm[3072 + row * 64 + col];
        float ev = p.eps[((size_t)t * BATCH + m0 + row) * ZD + col];
        zs[row * 72 + col] = (bf16)(em + ev * __expf(0.5f * es));
        float dm = em - pm;
        kacc += 1.f + es - dm * dm - __expf(es - ps);
      }
#pragma unroll
      for (int off = 32; off; off >>= 1) kacc += __shfl_down(kacc, off, 64);
      if (lane == 0) red[wv] = kacc;
      __syncthreads();
      if (tid == 0) {
        float ss = 0.f;
        for (int i = 0; i < 8; ++i) ss += red[i];
        p.KLD[t * 8 + s] = ss;
      }
      // phiz: A = zs (LDS), B = WPZ (LDS), N=1024 over 8 waves
      bf16x8 afz[2];
      afz[0] = *(const bf16x8*)(zs + r * 72 + kb * 8);
      afz[1] = *(const bf16x8*)(zs + r * 72 + 32 + kb * 8);
#pragma unroll 1
      for (int j = 0; j < 8; ++j) {
        int u = wv * 8 + j;
        f32x4 acc = {};
#pragma unroll
        for (int kk = 0; kk < 2; ++kk)
          acc = mfma16(afz[kk],
                       *(const bf16x8*)(lds + u * 2048 + ((((kk * 4 + kb) << 4) + r) << 4)),
                       acc);
        int gn = u * 16 + r;
#pragma unroll
        for (int qq = 0; qq < 4; ++qq) {
          int gm = m0 + kb * 4 + qq;
          p.PHIZ[(size_t)cur * BH + gm * HD + gn] = (bf16)fmaxf(acc[qq] + p.pz_b[gn], 0.f);
        }
      }
    } else if (p2n) {
      bool go = (p2kind == 0) || (p2kind == 3 ? (t > 0) : (t < SEQ - 1));
      if (go) {
        const bf16* A = (p2kind == 0) ? p.HB : (p2kind == 3) ? p.DECH : p.PHIX;
        bf16x8 af[32];
        load_af<32>(af, A, wv * 16 + r, 1024, 0, kb);
        float racc = 0.f;
        for (int u = 0; u < p2n; ++u) {
          f32x4 acc = unit_mma32(af, lds + p2off + u * 32768, kb, r);
          int id = p2id0 + u;
          int c = id * 16 + r;
#pragma unroll
          for (int qq = 0; qq < 4; ++qq) {
            int gm = wv * 16 + kb * 4 + qq;
            if (p2kind == 0) {
              p.DHP[(size_t)cur * BH + gm * HD + c] = (bf16)acc[qq];
            } else if (p2kind == 1) {
              p.ENCX[(size_t)oth * BH + gm * HD + c] = (bf16)(acc[qq] + p.enc_b[c]);
            } else if (p2kind == 2) {
              p.GIX[(size_t)oth * B3 + gm * 3072 + c] = acc[qq] + p.gru_bi[c];
            } else { // wd2: dec2 for t-1 + recon + sigmoid out
              float l = acc[qq] + p.dec2_b[c];
              size_t oi = ((size_t)(t - 1) * BATCH + gm) * XD + c;
              p.out[2 + oi] = sigmoidf_(l);
              float spp = fmaxf(l, 0.f) + log1pf(__expf(-fabsf(l)));
              racc += spp - p.x[oi] * l;
            }
          }
        }
        if (p2kind == 3) {
#pragma unroll
          for (int off = 32; off; off >>= 1) racc += __shfl_down(racc, off, 64);
          if (lane == 0) p.RPART[(t - 1) * 64 + p2id0 * 8 + wv] = racc;
        }
      }
    }
    gbar(p.BAR, ++bs);

    // ================= Phase 3: fused giz+GRU (K-split), wixb
    if (!special) {
      if (p3kind == 1) {
        const int khalf = wv >> 2;
        float* sc = (float*)(lds + scoff); // [4][3][256]
#pragma unroll 1
        for (int pass = 0; pass < 2; ++pass) {
          int mt = (wv & 3) + 4 * pass;
          bf16x8 af[16];
          load_af<16>(af, p.PHIZ + (size_t)cur * BH, mt * 16 + r, 1024, khalf * 512, kb);
          f32x4 a3[3] = {};
#pragma unroll
          for (int kk = 0; kk < 16; ++kk) {
            bf16x8 a = af[kk];
#pragma unroll
            for (int g = 0; g < 3; ++g)
              a3[g] = mfma16(a,
                             *(const bf16x8*)(lds + p3off + g * 32768 +
                                              (((((khalf * 16 + kk) * 4 + kb) << 4) + r) << 4)),
                             a3[g]);
          }
          if (khalf) {
#pragma unroll
            for (int g = 0; g < 3; ++g)
#pragma unroll
              for (int qq = 0; qq < 4; ++qq)
                sc[((wv & 3) * 3 + g) * 256 + (kb * 4 + qq) * 16 + r] = a3[g][qq];
          }
          __syncthreads();
          if (!khalf) {
            int c = p3id * 16 + r;
#pragma unroll
            for (int qq = 0; qq < 4; ++qq) {
              int gm = mt * 16 + kb * 4 + qq;
              int si = (kb * 4 + qq) * 16 + r;
              float ir = a3[0][qq] + sc[((wv & 3) * 3 + 0) * 256 + si] +
                         p.GIX[(size_t)cur * B3 + gm * 3072 + c];
              float iz = a3[1][qq] + sc[((wv & 3) * 3 + 1) * 256 + si] +
                         p.GIX[(size_t)cur * B3 + gm * 3072 + c + 1024];
              float in_ = a3[2][qq] + sc[((wv & 3) * 3 + 2) * 256 + si] +
                          p.GIX[(size_t)cur * B3 + gm * 3072 + c + 2048];
              float hr = p.GH[gm * 3072 + c], hz = p.GH[gm * 3072 + c + 1024],
                    hn = p.GH[gm * 3072 + c + 2048];
              float rr2 = sigmoidf_(ir + hr), zg = sigmoidf_(iz + hz);
              float nn = tanhf(in_ + rr2 * hn);
              float hv = p.H[gm * HD + c];
              float hnew = (1.f - zg) * nn + zg * hv;
              p.H[gm * HD + c] = hnew;
              p.HB[gm * HD + c] = (bf16)hnew;
            }
          }
          __syncthreads();
        }
      } else if (p3kind == 2 && t < SEQ - 1) {
        bf16x8 af[32];
        load_af<32>(af, p.PHIX, wv * 16 + r, 1024, 0, kb);
        f32x4 acc = unit_mma32(af, lds + p3off, kb, r);
        int c = 1536 + p3id * 16 + r;
#pragma unroll
        for (int qq = 0; qq < 4; ++qq) {
          int gm = wv * 16 + kb * 4 + qq;
          p.GIX[(size_t)oth * B3 + gm * 3072 + c] = acc[qq] + p.gru_bi[c];
        }
      }
    }
    gbar(p.BAR, ++bs);
  }
}

// ---------------- epilogue dec2 for t=255 -------------------------------------------
__global__ void dec2_last(const bf16* __restrict__ A, const bf16* __restrict__ W,
                          const float* __restrict__ x, const float* __restrict__ b2,
                          float* __restrict__ out, float* __restrict__ rpart) {
  const int lane = threadIdx.x & 63;
  const int r = lane & 15, kb = lane >> 4;
  const int w = blockIdx.x * 4 + (threadIdx.x >> 6); // 0..63
  const int m0 = (w & 7) * 16, n0 = (w >> 3) * 16;
  f32x4 acc[1][1] = {};
  const bf16* a0 = A + (size_t)(m0 + r) * HD + kb * 8;
  const bf16* b0 = W + (size_t)(n0 + r) * HD + kb * 8;
  mma_block<1, 1>(a0, 0, b0, (size_t)16 * HD, HD, acc);
  float racc = 0.f;
#pragma unroll
  for (int q = 0; q < 4; ++q) {
    int gm = m0 + kb * 4 + q, gn = n0 + r;
    float l = acc[0][0][q] + b2[gn];
    size_t oi = ((size_t)255 * BATCH + gm) * XD + gn;
    out[2 + oi] = sigmoidf_(l);
    float spp = fmaxf(l, 0.f) + log1pf(__expf(-fabsf(l)));
    racc += spp - x[oi] * l;
  }
#pragma unroll
  for (int off = 32; off; off >>= 1) racc += __shfl_down(racc, off, 64);
  if (lane == 0) rpart[255 * 64 + w] = racc;
}

__global__ void finalize_k(const float* __restrict__ rp, const float* __restrict__ kp,
                           float* __restrict__ out) {
  __shared__ float s[256];
  int tid = threadIdx.x;
  float a = 0.f;
  for (int i = tid; i < 256 * 64; i += 256) a += rp[i];
  s[tid] = a;
  __syncthreads();
  for (int off = 128; off > 0; off >>= 1) {
    if (tid < off) s[tid] += s[tid + off];
    __syncthreads();
  }
  if (tid == 0) out[0] = s[0] / (float)BATCH;
  __syncthreads();
  float bb = 0.f;
  for (int i = tid; i < 2048; i += 256) bb += kp[i];
  s[tid] = bb;
  __syncthreads();
  for (int off = 128; off > 0; off >>= 1) {
    if (tid < off) s[tid] += s[tid + off];
    __syncthreads();
  }
  if (tid == 0) out[1] = -0.5f * s[0] / (float)BATCH;
}

__global__ void sentinel_k(float* out) {
  if (threadIdx.x == 0) { out[0] = 1e9f; out[1] = 1e9f; }
}

// =====================================================================================
extern "C" void kernel_launch(void* const* d_in, const int* in_sizes, int n_in, void* d_out,
                              int out_size, void* d_ws, size_t ws_size, hipStream_t stream) {
  const float* x = (const float*)d_in[0];
  const float* eps = (const float*)d_in[1];
  const float* phi_x_W = (const float*)d_in[2];
  const float* phi_x_b = (const float*)d_in[3];
  const float* enc_W = (const float*)d_in[4];
  const float* enc_b = (const float*)d_in[5];
  const float* enc_mean_W = (const float*)d_in[6];
  const float* enc_mean_b = (const float*)d_in[7];
  const float* enc_std_W = (const float*)d_in[8];
  const float* enc_std_b = (const float*)d_in[9];
  const float* prior_W = (const float*)d_in[10];
  const float* prior_b = (const float*)d_in[11];
  const float* prior_mean_W = (const float*)d_in[12];
  const float* prior_mean_b = (const float*)d_in[13];
  const float* prior_std_W = (const float*)d_in[14];
  const float* prior_std_b = (const float*)d_in[15];
  const float* phi_z_W = (const float*)d_in[16];
  const float* phi_z_b = (const float*)d_in[17];
  const float* dec1_W = (const float*)d_in[18];
  const float* dec1_b = (const float*)d_in[19];
  const float* dec2_W = (const float*)d_in[20];
  const float* dec2_b = (const float*)d_in[21];
  const float* gru_Wi = (const float*)d_in[22];
  const float* gru_Wh = (const float*)d_in[23];
  const float* gru_bi = (const float*)d_in[24];
  const float* gru_bh = (const float*)d_in[25];
  float* out = (float*)d_out;

  char* w = (char*)d_ws;
  auto carve = [&](size_t bytes) {
    char* pp = w;
    w += (bytes + 255) & ~(size_t)255;
    return pp;
  };
  bf16* WA = (bf16*)carve((size_t)6144 * HD * 2);  // [prior;ench;gh;dhp] row-major [.][1024]
  bf16* WB = (bf16*)carve((size_t)256 * HD * 2);   // [pm;ps;em;es]
  bf16* WPZ = (bf16*)carve((size_t)HD * ZD * 2);
  bf16* WIZ = (bf16*)carve((size_t)3072 * HD * 2); // gru_Wi[:,1024:]
  bf16* WIX = (bf16*)carve((size_t)3072 * HD * 2); // gru_Wi[:,:1024]
  bf16* WXX = (bf16*)carve((size_t)HD * HD * 2);   // enc_W[:,:1024]
  bf16* WPX = (bf16*)carve((size_t)HD * XD * 2);
  bf16* WDZ = (bf16*)carve((size_t)HD * HD * 2);   // dec1_W[:,:1024]
  bf16* WD2 = (bf16*)carve((size_t)XD * HD * 2);
  bf16* XBF = (bf16*)carve((size_t)MROWS * XD * 2);
  float* H = (float*)carve((size_t)BH * 4);
  bf16* HB = (bf16*)carve((size_t)BH * 2);
  bf16* PT = (bf16*)carve((size_t)BH * 2);
  bf16* ET = (bf16*)carve((size_t)BH * 2);
  float* GH = (float*)carve((size_t)B3 * 4);
  bf16* PHIX = (bf16*)carve((size_t)BH * 2);
  bf16* ENCX = (bf16*)carve((size_t)2 * BH * 2);
  bf16* PHIZ = (bf16*)carve((size_t)2 * BH * 2);
  bf16* DHP = (bf16*)carve((size_t)2 * BH * 2);
  bf16* DECH = (bf16*)carve((size_t)BH * 2);
  float* GIX = (float*)carve((size_t)2 * B3 * 4);
  float* KLD = (float*)carve((size_t)SEQ * 8 * 4);
  float* RPART = (float*)carve((size_t)SEQ * 64 * 4);
  unsigned* BAR = (unsigned*)carve((size_t)NBLK * 32 * 4); // 128B-spaced flags
  if ((size_t)(w - (char*)d_ws) > ws_size) {
    sentinel_k<<<1, 64, 0, stream>>>(out);
    return;
  }

  auto cvt = [&](bf16* dst, const float* src, long n, int cols, int ld, int off) {
    int grid = (int)std::min((n + 255) / 256, (long)2048);
    cvt_k<<<grid, 256, 0, stream>>>(dst, src, n, cols, ld, off);
  };
  cvt(WA, prior_W, (long)HD * HD, HD, HD, 0);
  cvt(WA + (size_t)HD * HD, enc_W, (long)HD * HD, HD, 2 * HD, HD);
  cvt(WA + (size_t)2048 * HD, gru_Wh, (long)3072 * HD, HD, HD, 0);
  cvt(WA + (size_t)5120 * HD, dec1_W, (long)HD * HD, HD, 2 * HD, HD);
  cvt(WB, prior_mean_W, (long)ZD * HD, HD, HD, 0);
  cvt(WB + (size_t)64 * HD, prior_std_W, (long)ZD * HD, HD, HD, 0);
  cvt(WB + (size_t)128 * HD, enc_mean_W, (long)ZD * HD, HD, HD, 0);
  cvt(WB + (size_t)192 * HD, enc_std_W, (long)ZD * HD, HD, HD, 0);
  cvt(WPZ, phi_z_W, (long)HD * ZD, ZD, ZD, 0);
  cvt(WIZ, gru_Wi, (long)3072 * HD, HD, 2 * HD, HD);
  cvt(WIX, gru_Wi, (long)3072 * HD, HD, 2 * HD, 0);
  cvt(WXX, enc_W, (long)HD * HD, HD, 2 * HD, 0);
  cvt(WPX, phi_x_W, (long)HD * XD, XD, XD, 0);
  cvt(WDZ, dec1_W, (long)HD * HD, HD, 2 * HD, 0);
  cvt(WD2, dec2_W, (long)XD * HD, HD, HD, 0);
  cvt(XBF, x, (long)MROWS * XD, XD, XD, 0);

  hipMemsetAsync(H, 0, (size_t)BH * 4, stream);
  hipMemsetAsync(HB, 0, (size_t)BH * 2, stream);
  hipMemsetAsync(BAR, 0, (size_t)NBLK * 32 * 4, stream);

  // prologue: phi_x_0 -> encx_0, gix_0 (slot 0)
  Epi e1{PHIX, nullptr, phi_x_b, nullptr, 1, HD};
  gemm_bt<2, 2><<<32, 256, 0, stream>>>(XBF, XD, WPX, XD, BATCH, HD, XD, e1);
  Epi e2{ENCX, nullptr, enc_b, nullptr, 0, HD};
  gemm_bt<2, 2><<<32, 256, 0, stream>>>(PHIX, HD, WXX, HD, BATCH, HD, HD, e2);
  Epi e3{nullptr, GIX, gru_bi, nullptr, 0, 3072};
  gemm_bt<2, 2><<<96, 256, 0, stream>>>(PHIX, HD, WIX, HD, BATCH, 3072, HD, e3);

  LoopP lp;
  lp.WA = WA; lp.WB = WB; lp.WPZ = WPZ; lp.WIZ = WIZ; lp.WIX = WIX; lp.WXX = WXX;
  lp.WPX = WPX; lp.WDZ = WDZ; lp.WD2 = WD2; lp.XBF = XBF;
  lp.HB = HB; lp.PT = PT; lp.ET = ET; lp.PHIX = PHIX; lp.ENCX = ENCX; lp.PHIZ = PHIZ;
  lp.DHP = DHP; lp.DECH = DECH;
  lp.H = H; lp.GH = GH; lp.GIX = GIX; lp.KLD = KLD; lp.RPART = RPART; lp.out = out;
  lp.BAR = BAR;
  lp.eps = eps; lp.x = x;
  lp.prior_b = prior_b; lp.gru_bh = gru_bh; lp.gru_bi = gru_bi;
  lp.pm_b = prior_mean_b; lp.ps_b = prior_std_b; lp.em_b = enc_mean_b; lp.es_b = enc_std_b;
  lp.pz_b = phi_z_b; lp.phx_b = phi_x_b; lp.enc_b = enc_b; lp.dec1_b = dec1_b;
  lp.dec2_b = dec2_b;

  hipFuncSetAttribute(reinterpret_cast<const void*>(vrnn_loop),
                      hipFuncAttributeMaxDynamicSharedMemorySize, DYN_LDS);
  void* args[] = {&lp};
  hipLaunchCooperativeKernel(reinterpret_cast<const void*>(vrnn_loop), dim3(NBLK), dim3(512),
                             args, DYN_LDS, stream);

  // epilogue: dec1_255 (slot 1), dec2_255, losses
  Epi e4{DECH, nullptr, dec1_b, DHP + (size_t)1 * BH, 1, HD};
  gemm_bt<2, 2><<<32, 256, 0, stream>>>(PHIZ + (size_t)1 * BH, HD, WDZ, HD, BATCH, HD, HD, e4);
  dec2_last<<<16, 256, 0, stream>>>(DECH, WD2, x, dec2_b, out, RPART);
  finalize_k<<<1, 256, 0, stream>>>(RPART, KLD, out);
}